// Round 3
// baseline (23497.182 us; speedup 1.0000x reference)
//
#include <hip/hip_runtime.h>

typedef unsigned short ushort_t;

constexpr int TT = 1024;   // T;  B=4, H=1024, E=512, V=32000, W=8

// ---------------- helpers ----------------
__device__ __forceinline__ float blo(unsigned u) { return __uint_as_float(u << 16); }
__device__ __forceinline__ float bhi(unsigned u) { return __uint_as_float(u & 0xffff0000u); }
__device__ __forceinline__ ushort_t f2bf(float f) {
  unsigned u = __float_as_uint(f);
  unsigned r = (u + 0x7fffu + ((u >> 16) & 1u)) >> 16;  // RNE
  return (ushort_t)r;
}
__device__ __forceinline__ float tanh_fast(float x) {
  float ax = fabsf(x);
  float e = exp2f(ax * 2.885390081777927f);  // 2*log2(e)
  float r = 1.f - 2.f / (e + 1.f);
  return copysignf(r, x);
}

// Agent-scope (device-coherent, cross-XCD) data access. Emits sc1-flagged
// global_load/store that complete at the coherent point -- no L2 wb/inv needed.
__device__ __forceinline__ float ld_agent(const float* p) {
  return __hip_atomic_load(p, __ATOMIC_RELAXED, __HIP_MEMORY_SCOPE_AGENT);
}
__device__ __forceinline__ void st_agent(float* p, float v) {
  __hip_atomic_store(p, v, __ATOMIC_RELAXED, __HIP_MEMORY_SCOPE_AGENT);
}

// Lightweight grid barrier. Correctness argument:
//  - __syncthreads() emits s_waitcnt vmcnt(0) per wave before s_barrier, so ALL
//    of this block's agent-scope (sc1) stores are complete at the coherent
//    point before the leader arrives (sc1 store ack == coherent-point arrival).
//  - counter is monotonic (never reset inside the kernel; zeroed by a
//    hipMemsetAsync before launch -- re-zeroed on every graph replay since the
//    memset is part of the captured stream), target = 256 * barrier_index, so
//    there is no ABA; '<' tolerates faster blocks arriving at the next barrier
//    (max skew is 1 barrier by induction).
//  - all cross-barrier data is read with sc1 loads (coherent point), so no
//    buffer_inv is needed.
//  - asm compiler barriers pin program order: waves issue VMEM in order, so
//    once the instruction order is right, the sc1 data loads physically issue
//    after the spin observed the count.
__device__ __forceinline__ void gbar(unsigned* cnt, unsigned target) {
  __syncthreads();
  if (threadIdx.x == 0) {
    asm volatile("" ::: "memory");
    __hip_atomic_fetch_add(cnt, 1u, __ATOMIC_RELAXED, __HIP_MEMORY_SCOPE_AGENT);
    while (__hip_atomic_load(cnt, __ATOMIC_RELAXED, __HIP_MEMORY_SCOPE_AGENT) < target)
      __builtin_amdgcn_s_sleep(1);
    asm volatile("" ::: "memory");
  }
  __syncthreads();
}

// ---------------- generic tiled f32 GEMM:  C = scale*(A@W + bias) ----------------
// A: f32 (M,K) row-major, or gathered rows gA[gidx[m]] when gidx != null.
// W: f32 (K,N) row-major, leading dim ldw. M,N multiples of 64; K multiple of 16.
__global__ __launch_bounds__(256) void gemm_kernel(
    const float* __restrict__ A, const float* __restrict__ gA, const int* __restrict__ gidx,
    const float* __restrict__ W, int ldw,
    const float* __restrict__ bias, float scale,
    float* __restrict__ C, int M, int N, int K)
{
  __shared__ float As[16][68];
  __shared__ float Ws[16][68];
  int tid = threadIdx.x;
  int m0 = blockIdx.y * 64, n0 = blockIdx.x * 64;
  int tx = tid & 15, ty = tid >> 4;

  int am = tid >> 2;            // A-tile row 0..63
  int ak = (tid & 3) << 2;      // A-tile k  0,4,8,12
  int wk = tid >> 4;            // W-tile k  0..15
  int wn = (tid & 15) << 2;     // W-tile n  0..60
  int arow = m0 + am;
  const float* arow_p = (gidx != nullptr) ? &gA[(size_t)gidx[arow] * K] : &A[(size_t)arow * K];

  float acc[4][4];
#pragma unroll
  for (int i = 0; i < 4; ++i)
#pragma unroll
    for (int j = 0; j < 4; ++j) acc[i][j] = 0.f;

  for (int k0 = 0; k0 < K; k0 += 16) {
    float4 av = *(const float4*)&arow_p[k0 + ak];
    As[ak + 0][am] = av.x; As[ak + 1][am] = av.y;
    As[ak + 2][am] = av.z; As[ak + 3][am] = av.w;

    float4 wv = *(const float4*)&W[(size_t)(k0 + wk) * ldw + n0 + wn];
    Ws[wk][wn + 0] = wv.x; Ws[wk][wn + 1] = wv.y;
    Ws[wk][wn + 2] = wv.z; Ws[wk][wn + 3] = wv.w;
    __syncthreads();

#pragma unroll
    for (int kk = 0; kk < 16; ++kk) {
      float4 a4 = *(const float4*)&As[kk][ty << 2];
      float4 w4 = *(const float4*)&Ws[kk][tx << 2];
      float a_[4] = {a4.x, a4.y, a4.z, a4.w};
      float w_[4] = {w4.x, w4.y, w4.z, w4.w};
#pragma unroll
      for (int i = 0; i < 4; ++i)
#pragma unroll
        for (int j = 0; j < 4; ++j) acc[i][j] = fmaf(a_[i], w_[j], acc[i][j]);
    }
    __syncthreads();
  }

  int mbase = m0 + (ty << 2), nbase = n0 + (tx << 2);
  float bv4[4];
#pragma unroll
  for (int j = 0; j < 4; ++j) bv4[j] = bias[nbase + j];
#pragma unroll
  for (int i = 0; i < 4; ++i) {
    size_t ro = (size_t)(mbase + i) * N + nbase;
    float4 o;
    o.x = scale * (acc[i][0] + bv4[0]);
    o.y = scale * (acc[i][1] + bv4[1]);
    o.z = scale * (acc[i][2] + bv4[2]);
    o.w = scale * (acc[i][3] + bv4[3]);
    *(float4*)&C[ro] = o;
  }
}

// ---------------- persistent cooperative recurrence ----------------
// 256 blocks x 256 threads, 1 block/CU (100.6 KB LDS).
// Block bid owns stage-1 cols [bid*12, bid*12+12) of [a(2048)|g(1024)] and
// stage-2 cand cols [bid*4, +4). W1/W2/Wg2 bf16 in LDS; hn ping-pong in f32 LDS.
// Cross-block data (ag, hbuf) goes through agent-scope sc1 accesses; syncs are
// the lightweight gbar() above instead of cg grid.sync() (no L2 wb/inv).

constexpr int LDS_W1  = 0;        // ushort[12*2048] = 49152
constexpr int LDS_W2  = 49152;    // ushort[ 4*2048] = 16384
constexpr int LDS_WG2 = 65536;    // ushort[1024]    =  2048
constexpr int LDS_HN  = 67584;    // float [2*4*1024]= 32768
constexpr int LDS_RED = 100352;   // float [64]      =   256
constexpr int LDS_B2  = 100608;   // float [4]       =    16
constexpr int RC_LDS_BYTES = 100624;

__global__ __launch_bounds__(256) void recur_kernel(
    const float* __restrict__ W1c, const float* __restrict__ Wg1,
    const float* __restrict__ W2c, const float* __restrict__ b2c,
    const float* __restrict__ Wg2, const float* __restrict__ bg2,
    const float* __restrict__ preA, const float* __restrict__ preG,
    const float* __restrict__ preR,
    float* __restrict__ states, float* __restrict__ ag,
    float* __restrict__ hbuf, unsigned* __restrict__ barcnt)
{
  extern __shared__ char lds[];
  ushort_t* w1   = (ushort_t*)(lds + LDS_W1);   // [c][k] c<12, k<2048
  ushort_t* w2   = (ushort_t*)(lds + LDS_W2);   // [c][k] c<4
  ushort_t* wg2l = (ushort_t*)(lds + LDS_WG2);
  float*    hnf  = (float*)(lds + LDS_HN);      // [sel][b][k] ping-pong hn(t-1)/hn(t-2)
  float*    red  = (float*)(lds + LDS_RED);
  float*    b2l  = (float*)(lds + LDS_B2);

  int tid = threadIdx.x, bid = blockIdx.x;
  int ln = tid & 63, wv = tid >> 6;  // wave index = batch b
  int j0 = bid * 12, j2 = bid << 2;

  // ---- init: zero hn, stage weights (f32 -> bf16) into LDS ----
  for (int i = tid; i < 8192; i += 256) hnf[i] = 0.f;
  for (int i = tid; i < 12 * 2048; i += 256) {
    int c = i % 12, k = i / 12, j = j0 + c;
    float v = (j < 2048) ? W1c[(size_t)k * 2048 + j]
                         : Wg1[(size_t)k * 1024 + (j - 2048)];
    w1[c * 2048 + k] = f2bf(v);
  }
  for (int i = tid; i < 4 * 2048; i += 256) {
    int c = i & 3, k = i >> 2;
    w2[c * 2048 + k] = f2bf(W2c[(size_t)k * 1024 + j2 + c]);
  }
  for (int i = tid; i < 1024; i += 256) wg2l[i] = f2bf(Wg2[i]);
  if (tid < 4) b2l[tid] = b2c[j2 + tid];
  float bg2v = bg2[0];
  __syncthreads();

  int p = 0;

  for (int t = 0; t <= TT; ++t) {
    // ---- fused LayerNorm of h(t-1): every block, redundant ----
    if (t > 0) {
      float4 xv[4]; float mu_[4], rs_[4];
#pragma unroll
      for (int b = 0; b < 4; ++b) {
        const float* hp = &hbuf[(b << 10) + (tid << 2)];
        xv[b].x = ld_agent(hp + 0); xv[b].y = ld_agent(hp + 1);
        xv[b].z = ld_agent(hp + 2); xv[b].w = ld_agent(hp + 3);
        float s  = xv[b].x + xv[b].y + xv[b].z + xv[b].w;
        float s2 = xv[b].x * xv[b].x + xv[b].y * xv[b].y + xv[b].z * xv[b].z + xv[b].w * xv[b].w;
#pragma unroll
        for (int off = 32; off; off >>= 1) { s += __shfl_xor(s, off); s2 += __shfl_xor(s2, off); }
        if (ln == 0) { red[(wv << 3) + (b << 1)] = s; red[(wv << 3) + (b << 1) + 1] = s2; }
      }
      __syncthreads();
#pragma unroll
      for (int b = 0; b < 4; ++b) {
        float s  = red[(b << 1)] + red[8 + (b << 1)] + red[16 + (b << 1)] + red[24 + (b << 1)];
        float s2 = red[(b << 1) + 1] + red[8 + (b << 1) + 1] + red[16 + (b << 1) + 1] + red[24 + (b << 1) + 1];
        float mu = s * (1.f / 1024.f);
        float var = s2 * (1.f / 1024.f) - mu * mu;
        mu_[b] = mu; rs_[b] = rsqrtf(var + 1e-5f);
      }
      int np = p ^ 1;
#pragma unroll
      for (int b = 0; b < 4; ++b) {
        float4 xn;
        xn.x = (xv[b].x - mu_[b]) * rs_[b];
        xn.y = (xv[b].y - mu_[b]) * rs_[b];
        xn.z = (xv[b].z - mu_[b]) * rs_[b];
        xn.w = (xv[b].w - mu_[b]) * rs_[b];
        *(float4*)&hnf[np * 4096 + (b << 10) + (tid << 2)] = xn;
        if (tid == bid)  // thread bid's slice == this block's states slice
          *(float4*)&states[((size_t)((b << 10) + (t - 1)) << 10) + (bid << 2)] = xn;
      }
      p = np;
      __syncthreads();
    }
    if (t == TT) break;

    // ---- phase 1: this block's 12 a/g columns.  K-vec = [hn(t-1) | hn(t-2)] ----
    {
      int b = wv;
      const float* pA = preA + ((size_t)((b << 10) + t) << 11);  // row * 2048
      const float* pG = preG + ((size_t)((b << 10) + t) << 10);  // row * 1024
      float acc[12];
#pragma unroll
      for (int c = 0; c < 12; ++c) acc[c] = 0.f;
      for (int k0 = 0; k0 < 2048; k0 += 256) {
        int kk = k0 + (ln << 2);
        int sel = (k0 < 1024) ? p : (p ^ 1);
        float4 hv = *(const float4*)&hnf[sel * 4096 + (b << 10) + (kk & 1023)];
#pragma unroll
        for (int c = 0; c < 12; ++c) {
          uint2 wq = *(const uint2*)&w1[c * 2048 + kk];
          float a = acc[c];
          a = fmaf(blo(wq.x), hv.x, a); a = fmaf(bhi(wq.x), hv.y, a);
          a = fmaf(blo(wq.y), hv.z, a); a = fmaf(bhi(wq.y), hv.w, a);
          acc[c] = a;
        }
      }
#pragma unroll
      for (int c = 0; c < 12; ++c) {
        float v = acc[c];
#pragma unroll
        for (int off = 32; off; off >>= 1) v += __shfl_xor(v, off);
        acc[c] = v;
      }
      if (ln < 12) {
        float v = acc[0];
#pragma unroll
        for (int c = 1; c < 12; ++c) if (ln == c) v = acc[c];
        int j = j0 + ln;
        float pre = (j < 2048) ? pA[j] : pG[j - 2048];
        st_agent(&ag[b * 3072 + j], v + pre);
      }
    }
    gbar(barcnt, (unsigned)(2 * t + 1) << 8);

    // ---- phase 2: gate (redundant per block) + 4 cand columns + h ----
    {
      int b = wv;
      const float* agv = ag + b * 3072;
      float gs = 0.f;
#pragma unroll
      for (int i = 0; i < 4; ++i) {
        int gi = ((i << 6) + ln) << 2;
        const float* gp = &agv[2048 + gi];
        float g0 = ld_agent(gp + 0), g1 = ld_agent(gp + 1);
        float g2 = ld_agent(gp + 2), g3 = ld_agent(gp + 3);
        uint2 wq = *(const uint2*)&wg2l[gi];
        gs = fmaf(tanh_fast(g0), blo(wq.x), gs);
        gs = fmaf(tanh_fast(g1), bhi(wq.x), gs);
        gs = fmaf(tanh_fast(g2), blo(wq.y), gs);
        gs = fmaf(tanh_fast(g3), bhi(wq.y), gs);
      }
#pragma unroll
      for (int off = 32; off; off >>= 1) gs += __shfl_xor(gs, off);
      float gate = 1.f / (1.f + exp2f(-1.4426950408889634f * (gs + bg2v)));

      float acc2[4] = {0.f, 0.f, 0.f, 0.f};
      for (int k0 = 0; k0 < 2048; k0 += 256) {
        int kk = k0 + (ln << 2);
        const float* ap = &agv[kk];
        float a0 = fmaxf(ld_agent(ap + 0), 0.f);
        float a1 = fmaxf(ld_agent(ap + 1), 0.f);
        float a2 = fmaxf(ld_agent(ap + 2), 0.f);
        float a3 = fmaxf(ld_agent(ap + 3), 0.f);
#pragma unroll
        for (int c = 0; c < 4; ++c) {
          uint2 wq = *(const uint2*)&w2[c * 2048 + kk];
          float a = acc2[c];
          a = fmaf(blo(wq.x), a0, a); a = fmaf(bhi(wq.x), a1, a);
          a = fmaf(blo(wq.y), a2, a); a = fmaf(bhi(wq.y), a3, a);
          acc2[c] = a;
        }
      }
#pragma unroll
      for (int c = 0; c < 4; ++c) {
        float v = acc2[c];
#pragma unroll
        for (int off = 32; off; off >>= 1) v += __shfl_xor(v, off);
        acc2[c] = v;
      }
      if (ln < 4) {
        float cand = acc2[0];
#pragma unroll
        for (int c = 1; c < 4; ++c) if (ln == c) cand = acc2[c];
        cand += b2l[ln];
        int j = j2 + ln;
        float h1v = hnf[p * 4096 + (b << 10) + j];   // h1 = hn(t-1)
        float pr = preR[((size_t)((b << 10) + t) << 10) + j];
        st_agent(&hbuf[(b << 10) + j], h1v + gate * cand + pr);
      }
    }
    gbar(barcnt, (unsigned)(2 * t + 2) << 8);
  }
}

// ---------------- windowed attention (W=8, 9 taps) ----------------
__global__ __launch_bounds__(256) void attn_kernel(
    const float* __restrict__ q, const float* __restrict__ kk,
    const float* __restrict__ vv, float* __restrict__ o)
{
  int m = blockIdx.x;           // b*T + t
  int t = m & 1023;
  int tid = threadIdx.x;
  int ln = tid & 63, wvv = tid >> 6;
  int c0 = tid << 2;
  __shared__ float sred[36];

  float4 qv = *(const float4*)&q[((size_t)m << 10) + c0];
#pragma unroll
  for (int w = 0; w < 9; ++w) {
    int src = t + w - 8;
    float s = 0.f;
    if (src >= 0) {
      float4 kv = *(const float4*)&kk[((size_t)(m + w - 8) << 10) + c0];
      s = qv.x * kv.x + qv.y * kv.y + qv.z * kv.z + qv.w * kv.w;
    }
#pragma unroll
    for (int off = 32; off; off >>= 1) s += __shfl_xor(s, off);
    if (ln == 0) sred[w * 4 + wvv] = s;
  }
  __syncthreads();

  float p[9], mx = -3.4e38f;
#pragma unroll
  for (int w = 0; w < 9; ++w) {
    if (t + w - 8 >= 0) {
      float sc = (sred[w * 4] + sred[w * 4 + 1] + sred[w * 4 + 2] + sred[w * 4 + 3]) * 0.03125f;
      p[w] = sc; mx = fmaxf(mx, sc);
    } else p[w] = -3.4e38f;
  }
  float den = 0.f;
#pragma unroll
  for (int w = 0; w < 9; ++w) {
    float e = (t + w - 8 >= 0) ? exp2f(1.4426950408889634f * (p[w] - mx)) : 0.f;
    p[w] = e; den += e;
  }
  float inv = 1.f / den;
  float4 acc = {0.f, 0.f, 0.f, 0.f};
#pragma unroll
  for (int w = 0; w < 9; ++w) {
    if (t + w - 8 >= 0) {
      float4 vr = *(const float4*)&vv[((size_t)(m + w - 8) << 10) + c0];
      float pw = p[w] * inv;
      acc.x = fmaf(pw, vr.x, acc.x); acc.y = fmaf(pw, vr.y, acc.y);
      acc.z = fmaf(pw, vr.z, acc.z); acc.w = fmaf(pw, vr.w, acc.w);
    }
  }
  *(float4*)&o[((size_t)m << 10) + c0] = acc;
}

// ---------------- workspace layout (bytes) ----------------
constexpr size_t OFF_STATES = 0;                       // 4096*1024 f32 = 16.8 MB
constexpr size_t OFF_PREA   = 16777216;                // 4096*2048 f32 = 33.5 MB
constexpr size_t OFF_PREG   = 50331648;                // 16.8 MB
constexpr size_t OFF_PRER   = 67108864;                // 16.8 MB
constexpr size_t OFF_AG     = 83886080;                // 4*3072 f32
constexpr size_t OFF_HB     = 83935232;                // 4*1024 f32
constexpr size_t OFF_CNT    = 83951616;                // barrier counter (u32)
constexpr size_t NEED_WS    = 83951744;

extern "C" void kernel_launch(void* const* d_in, const int* in_sizes, int n_in,
                              void* d_out, int out_size, void* d_ws, size_t ws_size,
                              hipStream_t stream) {
  const int*   x   = (const int*)d_in[0];
  const float* emb = (const float*)d_in[1];
  const float* W1c = (const float*)d_in[2];
  const float* b1c = (const float*)d_in[3];
  const float* W2c = (const float*)d_in[4];
  const float* b2c = (const float*)d_in[5];
  const float* Wg1 = (const float*)d_in[6];
  const float* bg1 = (const float*)d_in[7];
  const float* Wg2 = (const float*)d_in[8];
  const float* bg2 = (const float*)d_in[9];
  const float* Wr  = (const float*)d_in[10];
  const float* br  = (const float*)d_in[11];
  const float* Wk  = (const float*)d_in[12];
  const float* bk  = (const float*)d_in[13];
  const float* Wq  = (const float*)d_in[14];
  const float* bq  = (const float*)d_in[15];
  const float* Wv  = (const float*)d_in[16];
  const float* bv  = (const float*)d_in[17];
  const float* Wf  = (const float*)d_in[18];
  const float* bfv = (const float*)d_in[19];

  if (ws_size < NEED_WS) return;
  char* ws = (char*)d_ws;
  float* states = (float*)(ws + OFF_STATES);
  float* preA = (float*)(ws + OFF_PREA);
  float* preG = (float*)(ws + OFF_PREG);
  float* preR = (float*)(ws + OFF_PRER);
  float* agb  = (float*)(ws + OFF_AG);
  float* hbuf = (float*)(ws + OFF_HB);
  unsigned* barcnt = (unsigned*)(ws + OFF_CNT);

  dim3 blk(256);
  // zero the barrier counter (graph-capture-safe; replayed each graph launch)
  hipMemsetAsync(barcnt, 0, sizeof(unsigned), stream);

  // precompute et-dependent parts (gathered-embedding GEMMs, K=512), biases folded in
  gemm_kernel<<<dim3(32, 64), blk, 0, stream>>>(nullptr, emb, x, W1c + (size_t)2048 * 2048, 2048,
                                                b1c, 1.f, preA, 4096, 2048, 512);
  gemm_kernel<<<dim3(16, 64), blk, 0, stream>>>(nullptr, emb, x, Wg1 + (size_t)2048 * 1024, 1024,
                                                bg1, 1.f, preG, 4096, 1024, 512);
  gemm_kernel<<<dim3(16, 64), blk, 0, stream>>>(nullptr, emb, x, Wr, 1024,
                                                br, 0.1f, preR, 4096, 1024, 512);

  // persistent cooperative recurrence (cooperative launch only for co-residency)
  hipFuncSetAttribute((const void*)recur_kernel,
                      hipFuncAttributeMaxDynamicSharedMemorySize, RC_LDS_BYTES);
  void* args[] = {(void*)&W1c, (void*)&Wg1, (void*)&W2c, (void*)&b2c, (void*)&Wg2, (void*)&bg2,
                  (void*)&preA, (void*)&preG, (void*)&preR,
                  (void*)&states, (void*)&agb, (void*)&hbuf, (void*)&barcnt};
  hipLaunchCooperativeKernel((const void*)recur_kernel, dim3(256), dim3(256),
                             args, RC_LDS_BYTES, stream);

  // q/k/v reuse the pre-buffers (no longer needed after the scan)
  float* qb = preA;
  float* kb = preA + 4194304;   // second 16.8 MB half of preA
  float* vb = preG;
  float* ab = preR;
  gemm_kernel<<<dim3(16, 64), blk, 0, stream>>>(states, nullptr, nullptr, Wq, 1024,
                                                bq, 1.f, qb, 4096, 1024, 1024);
  gemm_kernel<<<dim3(16, 64), blk, 0, stream>>>(states, nullptr, nullptr, Wk, 1024,
                                                bk, 1.f, kb, 4096, 1024, 1024);
  gemm_kernel<<<dim3(16, 64), blk, 0, stream>>>(states, nullptr, nullptr, Wv, 1024,
                                                bv, 1.f, vb, 4096, 1024, 1024);
  attn_kernel<<<dim3(4096), blk, 0, stream>>>(qb, kb, vb, ab);
  // final 268-GFLOP output GEMM
  gemm_kernel<<<dim3(500, 64), blk, 0, stream>>>(ab, nullptr, nullptr, Wf, 32000,
                                                 bfv, 1.f, (float*)d_out, 4096, 32000, 1024);
}

// Round 4
// 17862.059 us; speedup vs baseline: 1.3155x; 1.3155x over previous
//
#include <hip/hip_runtime.h>

typedef unsigned short ushort_t;

constexpr int TT = 1024;   // T;  B=4, H=1024, E=512, V=32000, W=8

// ---------------- helpers ----------------
__device__ __forceinline__ float blo(unsigned u) { return __uint_as_float(u << 16); }
__device__ __forceinline__ float bhi(unsigned u) { return __uint_as_float(u & 0xffff0000u); }
__device__ __forceinline__ ushort_t f2bf(float f) {
  unsigned u = __float_as_uint(f);
  unsigned r = (u + 0x7fffu + ((u >> 16) & 1u)) >> 16;  // RNE
  return (ushort_t)r;
}
__device__ __forceinline__ float tanh_fast(float x) {
  float ax = fabsf(x);
  float e = exp2f(ax * 2.885390081777927f);  // 2*log2(e)
  float r = 1.f - 2.f / (e + 1.f);
  return copysignf(r, x);
}

// Agent-scope (device-coherent, cross-XCD) scalar access (sc1 path).
__device__ __forceinline__ void st_agent(float* p, float v) {
  __hip_atomic_store(p, v, __ATOMIC_RELAXED, __HIP_MEMORY_SCOPE_AGENT);
}

// Batched coherent 16B loads: issue N dwordx4 sc0 sc1 loads, ONE vmcnt drain.
// (sc0=bypass L1, sc1=bypass per-XCD L2 -> read at coherent point/MALL.)
__device__ __forceinline__ void ldg_hb4(const float* p0, const float* p1,
                                        const float* p2, const float* p3,
                                        float4& r0, float4& r1, float4& r2, float4& r3)
{
  asm volatile(
    "global_load_dwordx4 %0, %4, off sc0 sc1\n\t"
    "global_load_dwordx4 %1, %5, off sc0 sc1\n\t"
    "global_load_dwordx4 %2, %6, off sc0 sc1\n\t"
    "global_load_dwordx4 %3, %7, off sc0 sc1\n\t"
    "s_waitcnt vmcnt(0)"
    : "=&v"(r0), "=&v"(r1), "=&v"(r2), "=&v"(r3)
    : "v"(p0), "v"(p1), "v"(p2), "v"(p3)
    : "memory");
}

// Phase-2 bundle: 4 gate chunks (gbase + i*1024B) + 8 cand chunks
// (cbase + i*1024B, i<8 via two bases). 12 loads in flight, one drain.
__device__ __forceinline__ void ldg_phase2(
    const float* gbase, const float* cbase,
    float4& g0, float4& g1, float4& g2, float4& g3,
    float4& a0, float4& a1, float4& a2, float4& a3,
    float4& a4, float4& a5, float4& a6, float4& a7)
{
  const float* cbase2 = cbase + 1024;  // +4096 B
  asm volatile(
    "global_load_dwordx4 %0, %12, off sc0 sc1\n\t"
    "global_load_dwordx4 %1, %12, off offset:1024 sc0 sc1\n\t"
    "global_load_dwordx4 %2, %12, off offset:2048 sc0 sc1\n\t"
    "global_load_dwordx4 %3, %12, off offset:3072 sc0 sc1\n\t"
    "global_load_dwordx4 %4, %13, off sc0 sc1\n\t"
    "global_load_dwordx4 %5, %13, off offset:1024 sc0 sc1\n\t"
    "global_load_dwordx4 %6, %13, off offset:2048 sc0 sc1\n\t"
    "global_load_dwordx4 %7, %13, off offset:3072 sc0 sc1\n\t"
    "global_load_dwordx4 %8, %14, off sc0 sc1\n\t"
    "global_load_dwordx4 %9, %14, off offset:1024 sc0 sc1\n\t"
    "global_load_dwordx4 %10, %14, off offset:2048 sc0 sc1\n\t"
    "global_load_dwordx4 %11, %14, off offset:3072 sc0 sc1\n\t"
    "s_waitcnt vmcnt(0)"
    : "=&v"(g0), "=&v"(g1), "=&v"(g2), "=&v"(g3),
      "=&v"(a0), "=&v"(a1), "=&v"(a2), "=&v"(a3),
      "=&v"(a4), "=&v"(a5), "=&v"(a6), "=&v"(a7)
    : "v"(gbase), "v"(cbase), "v"(cbase2)
    : "memory");
}

// ---- hierarchical grid barrier ----
// Layout (u32 units): gcnt at bars[0]; group-g counter at bars[(g+1)*128]
// (512 B apart -> independent cachelines, parallel RMW chains at the MALL).
// idx = barrier ordinal (monotonic, 0-based). Group = bid>>5 (8 groups x 32).
// Arrive chain depth: 32 (parallel across 8 lines) + 8, vs 256 before.
// __syncthreads drains vmcnt -> all sc1 data stores complete before arrive.
__device__ __forceinline__ void gbar(unsigned* bars, int idx) {
  __syncthreads();
  if (threadIdx.x == 0) {
    asm volatile("" ::: "memory");
    unsigned g = blockIdx.x >> 5;
    unsigned* gc = bars + ((g + 1u) << 7);
    unsigned old = __hip_atomic_fetch_add(gc, 1u, __ATOMIC_RELAXED, __HIP_MEMORY_SCOPE_AGENT);
    if (old == (unsigned)(idx * 32 + 31))
      __hip_atomic_fetch_add(bars, 1u, __ATOMIC_RELAXED, __HIP_MEMORY_SCOPE_AGENT);
    unsigned tgt = (unsigned)(idx * 8 + 8);
    while (__hip_atomic_load(bars, __ATOMIC_RELAXED, __HIP_MEMORY_SCOPE_AGENT) < tgt)
      __builtin_amdgcn_s_sleep(1);
    asm volatile("" ::: "memory");
  }
  __syncthreads();
}

// ---------------- generic tiled f32 GEMM:  C = scale*(A@W + bias) ----------------
// A: f32 (M,K) row-major, or gathered rows gA[gidx[m]] when gidx != null.
// W: f32 (K,N) row-major, leading dim ldw. M,N multiples of 64; K multiple of 16.
__global__ __launch_bounds__(256) void gemm_kernel(
    const float* __restrict__ A, const float* __restrict__ gA, const int* __restrict__ gidx,
    const float* __restrict__ W, int ldw,
    const float* __restrict__ bias, float scale,
    float* __restrict__ C, int M, int N, int K)
{
  __shared__ float As[16][68];
  __shared__ float Ws[16][68];
  int tid = threadIdx.x;
  int m0 = blockIdx.y * 64, n0 = blockIdx.x * 64;
  int tx = tid & 15, ty = tid >> 4;

  int am = tid >> 2;            // A-tile row 0..63
  int ak = (tid & 3) << 2;      // A-tile k  0,4,8,12
  int wk = tid >> 4;            // W-tile k  0..15
  int wn = (tid & 15) << 2;     // W-tile n  0..60
  int arow = m0 + am;
  const float* arow_p = (gidx != nullptr) ? &gA[(size_t)gidx[arow] * K] : &A[(size_t)arow * K];

  float acc[4][4];
#pragma unroll
  for (int i = 0; i < 4; ++i)
#pragma unroll
    for (int j = 0; j < 4; ++j) acc[i][j] = 0.f;

  for (int k0 = 0; k0 < K; k0 += 16) {
    float4 av = *(const float4*)&arow_p[k0 + ak];
    As[ak + 0][am] = av.x; As[ak + 1][am] = av.y;
    As[ak + 2][am] = av.z; As[ak + 3][am] = av.w;

    float4 wv = *(const float4*)&W[(size_t)(k0 + wk) * ldw + n0 + wn];
    Ws[wk][wn + 0] = wv.x; Ws[wk][wn + 1] = wv.y;
    Ws[wk][wn + 2] = wv.z; Ws[wk][wn + 3] = wv.w;
    __syncthreads();

#pragma unroll
    for (int kk = 0; kk < 16; ++kk) {
      float4 a4 = *(const float4*)&As[kk][ty << 2];
      float4 w4 = *(const float4*)&Ws[kk][tx << 2];
      float a_[4] = {a4.x, a4.y, a4.z, a4.w};
      float w_[4] = {w4.x, w4.y, w4.z, w4.w};
#pragma unroll
      for (int i = 0; i < 4; ++i)
#pragma unroll
        for (int j = 0; j < 4; ++j) acc[i][j] = fmaf(a_[i], w_[j], acc[i][j]);
    }
    __syncthreads();
  }

  int mbase = m0 + (ty << 2), nbase = n0 + (tx << 2);
  float bv4[4];
#pragma unroll
  for (int j = 0; j < 4; ++j) bv4[j] = bias[nbase + j];
#pragma unroll
  for (int i = 0; i < 4; ++i) {
    size_t ro = (size_t)(mbase + i) * N + nbase;
    float4 o;
    o.x = scale * (acc[i][0] + bv4[0]);
    o.y = scale * (acc[i][1] + bv4[1]);
    o.z = scale * (acc[i][2] + bv4[2]);
    o.w = scale * (acc[i][3] + bv4[3]);
    *(float4*)&C[ro] = o;
  }
}

// ---------------- persistent cooperative recurrence ----------------
// 256 blocks x 256 threads, 1 block/CU (100.6 KB LDS).
// Block bid owns stage-1 cols [bid*12, bid*12+12) of [a(2048)|g(1024)] and
// stage-2 cand cols [bid*4, +4). W1/W2/Wg2 bf16 in LDS; hn ping-pong in f32 LDS.
// Cross-block data (ag, hbuf): sc1 stores + batched dwordx4 sc0/sc1 loads.
// Sync: hierarchical gbar() (8x32 arrive trees), 2 per step.

constexpr int LDS_W1  = 0;        // ushort[12*2048] = 49152
constexpr int LDS_W2  = 49152;    // ushort[ 4*2048] = 16384
constexpr int LDS_WG2 = 65536;    // ushort[1024]    =  2048
constexpr int LDS_HN  = 67584;    // float [2*4*1024]= 32768
constexpr int LDS_RED = 100352;   // float [64]      =   256
constexpr int LDS_B2  = 100608;   // float [4]       =    16
constexpr int RC_LDS_BYTES = 100624;

__global__ __launch_bounds__(256) void recur_kernel(
    const float* __restrict__ W1c, const float* __restrict__ Wg1,
    const float* __restrict__ W2c, const float* __restrict__ b2c,
    const float* __restrict__ Wg2, const float* __restrict__ bg2,
    const float* __restrict__ preA, const float* __restrict__ preG,
    const float* __restrict__ preR,
    float* __restrict__ states, float* __restrict__ ag,
    float* __restrict__ hbuf, unsigned* __restrict__ barcnt)
{
  extern __shared__ char lds[];
  ushort_t* w1   = (ushort_t*)(lds + LDS_W1);   // [c][k] c<12, k<2048
  ushort_t* w2   = (ushort_t*)(lds + LDS_W2);   // [c][k] c<4
  ushort_t* wg2l = (ushort_t*)(lds + LDS_WG2);
  float*    hnf  = (float*)(lds + LDS_HN);      // [sel][b][k] ping-pong hn(t-1)/hn(t-2)
  float*    red  = (float*)(lds + LDS_RED);
  float*    b2l  = (float*)(lds + LDS_B2);

  int tid = threadIdx.x, bid = blockIdx.x;
  int ln = tid & 63, wv = tid >> 6;  // wave index = batch b
  int j0 = bid * 12, j2 = bid << 2;

  // ---- init: zero hn, stage weights (f32 -> bf16) into LDS ----
  for (int i = tid; i < 8192; i += 256) hnf[i] = 0.f;
  for (int i = tid; i < 12 * 2048; i += 256) {
    int c = i % 12, k = i / 12, j = j0 + c;
    float v = (j < 2048) ? W1c[(size_t)k * 2048 + j]
                         : Wg1[(size_t)k * 1024 + (j - 2048)];
    w1[c * 2048 + k] = f2bf(v);
  }
  for (int i = tid; i < 4 * 2048; i += 256) {
    int c = i & 3, k = i >> 2;
    w2[c * 2048 + k] = f2bf(W2c[(size_t)k * 1024 + j2 + c]);
  }
  for (int i = tid; i < 1024; i += 256) wg2l[i] = f2bf(Wg2[i]);
  if (tid < 4) b2l[tid] = b2c[j2 + tid];
  float bg2v = bg2[0];
  __syncthreads();

  int p = 0;

  for (int t = 0; t <= TT; ++t) {
    // ---- fused LayerNorm of h(t-1): every block, redundant ----
    if (t > 0) {
      float4 xv[4]; float mu_[4], rs_[4];
      ldg_hb4(&hbuf[(0 << 10) + (tid << 2)], &hbuf[(1 << 10) + (tid << 2)],
              &hbuf[(2 << 10) + (tid << 2)], &hbuf[(3 << 10) + (tid << 2)],
              xv[0], xv[1], xv[2], xv[3]);
#pragma unroll
      for (int b = 0; b < 4; ++b) {
        float s  = xv[b].x + xv[b].y + xv[b].z + xv[b].w;
        float s2 = xv[b].x * xv[b].x + xv[b].y * xv[b].y + xv[b].z * xv[b].z + xv[b].w * xv[b].w;
#pragma unroll
        for (int off = 32; off; off >>= 1) { s += __shfl_xor(s, off); s2 += __shfl_xor(s2, off); }
        if (ln == 0) { red[(wv << 3) + (b << 1)] = s; red[(wv << 3) + (b << 1) + 1] = s2; }
      }
      __syncthreads();
#pragma unroll
      for (int b = 0; b < 4; ++b) {
        float s  = red[(b << 1)] + red[8 + (b << 1)] + red[16 + (b << 1)] + red[24 + (b << 1)];
        float s2 = red[(b << 1) + 1] + red[8 + (b << 1) + 1] + red[16 + (b << 1) + 1] + red[24 + (b << 1) + 1];
        float mu = s * (1.f / 1024.f);
        float var = s2 * (1.f / 1024.f) - mu * mu;
        mu_[b] = mu; rs_[b] = rsqrtf(var + 1e-5f);
      }
      int np = p ^ 1;
#pragma unroll
      for (int b = 0; b < 4; ++b) {
        float4 xn;
        xn.x = (xv[b].x - mu_[b]) * rs_[b];
        xn.y = (xv[b].y - mu_[b]) * rs_[b];
        xn.z = (xv[b].z - mu_[b]) * rs_[b];
        xn.w = (xv[b].w - mu_[b]) * rs_[b];
        *(float4*)&hnf[np * 4096 + (b << 10) + (tid << 2)] = xn;
        if (tid == bid)  // thread bid's slice == this block's states slice
          *(float4*)&states[((size_t)((b << 10) + (t - 1)) << 10) + (bid << 2)] = xn;
      }
      p = np;
      __syncthreads();
    }
    if (t == TT) break;

    // ---- phase 1: this block's 12 a/g columns.  K-vec = [hn(t-1) | hn(t-2)] ----
    {
      int b = wv;
      const float* pA = preA + ((size_t)((b << 10) + t) << 11);  // row * 2048
      const float* pG = preG + ((size_t)((b << 10) + t) << 10);  // row * 1024
      // hoisted pre load: issues early, hides under the k-loop
      float pre = 0.f;
      if (ln < 12) {
        int j = j0 + ln;
        pre = (j < 2048) ? pA[j] : pG[j - 2048];
      }
      float acc[12];
#pragma unroll
      for (int c = 0; c < 12; ++c) acc[c] = 0.f;
      for (int k0 = 0; k0 < 2048; k0 += 256) {
        int kk = k0 + (ln << 2);
        int sel = (k0 < 1024) ? p : (p ^ 1);
        float4 hv = *(const float4*)&hnf[sel * 4096 + (b << 10) + (kk & 1023)];
#pragma unroll
        for (int c = 0; c < 12; ++c) {
          uint2 wq = *(const uint2*)&w1[c * 2048 + kk];
          float a = acc[c];
          a = fmaf(blo(wq.x), hv.x, a); a = fmaf(bhi(wq.x), hv.y, a);
          a = fmaf(blo(wq.y), hv.z, a); a = fmaf(bhi(wq.y), hv.w, a);
          acc[c] = a;
        }
      }
#pragma unroll
      for (int c = 0; c < 12; ++c) {
        float v = acc[c];
#pragma unroll
        for (int off = 32; off; off >>= 1) v += __shfl_xor(v, off);
        acc[c] = v;
      }
      if (ln < 12) {
        float v = acc[0];
#pragma unroll
        for (int c = 1; c < 12; ++c) if (ln == c) v = acc[c];
        st_agent(&ag[b * 3072 + j0 + ln], v + pre);
      }
    }
    gbar(barcnt, 2 * t);

    // ---- phase 2: gate (redundant per block) + 4 cand columns + h ----
    {
      int b = wv;
      const float* agv = ag + b * 3072;
      // hoisted preR load
      float pr = 0.f;
      if (ln < 4) pr = preR[((size_t)((b << 10) + t) << 10) + j2 + ln];

      float4 g0, g1, g2, g3, a0, a1, a2, a3, a4, a5, a6, a7;
      ldg_phase2(agv + 2048 + (ln << 2), agv + (ln << 2),
                 g0, g1, g2, g3, a0, a1, a2, a3, a4, a5, a6, a7);
      float4 gv_[4] = {g0, g1, g2, g3};
      float4 av_[8] = {a0, a1, a2, a3, a4, a5, a6, a7};

      float gs = 0.f;
#pragma unroll
      for (int i = 0; i < 4; ++i) {
        int gi = ((i << 6) + ln) << 2;
        uint2 wq = *(const uint2*)&wg2l[gi];
        gs = fmaf(tanh_fast(gv_[i].x), blo(wq.x), gs);
        gs = fmaf(tanh_fast(gv_[i].y), bhi(wq.x), gs);
        gs = fmaf(tanh_fast(gv_[i].z), blo(wq.y), gs);
        gs = fmaf(tanh_fast(gv_[i].w), bhi(wq.y), gs);
      }
#pragma unroll
      for (int off = 32; off; off >>= 1) gs += __shfl_xor(gs, off);
      float gate = 1.f / (1.f + exp2f(-1.4426950408889634f * (gs + bg2v)));

      float acc2[4] = {0.f, 0.f, 0.f, 0.f};
#pragma unroll
      for (int i = 0; i < 8; ++i) {
        int kk = (i << 8) + (ln << 2);
        float ax = fmaxf(av_[i].x, 0.f), ay = fmaxf(av_[i].y, 0.f);
        float az = fmaxf(av_[i].z, 0.f), aw = fmaxf(av_[i].w, 0.f);
#pragma unroll
        for (int c = 0; c < 4; ++c) {
          uint2 wq = *(const uint2*)&w2[c * 2048 + kk];
          float a = acc2[c];
          a = fmaf(blo(wq.x), ax, a); a = fmaf(bhi(wq.x), ay, a);
          a = fmaf(blo(wq.y), az, a); a = fmaf(bhi(wq.y), aw, a);
          acc2[c] = a;
        }
      }
#pragma unroll
      for (int c = 0; c < 4; ++c) {
        float v = acc2[c];
#pragma unroll
        for (int off = 32; off; off >>= 1) v += __shfl_xor(v, off);
        acc2[c] = v;
      }
      if (ln < 4) {
        float cand = acc2[0];
#pragma unroll
        for (int c = 1; c < 4; ++c) if (ln == c) cand = acc2[c];
        cand += b2l[ln];
        float h1v = hnf[p * 4096 + (b << 10) + j2 + ln];   // h1 = hn(t-1)
        st_agent(&hbuf[(b << 10) + j2 + ln], h1v + gate * cand + pr);
      }
    }
    gbar(barcnt, 2 * t + 1);
  }
}

// ---------------- windowed attention (W=8, 9 taps) ----------------
__global__ __launch_bounds__(256) void attn_kernel(
    const float* __restrict__ q, const float* __restrict__ kk,
    const float* __restrict__ vv, float* __restrict__ o)
{
  int m = blockIdx.x;           // b*T + t
  int t = m & 1023;
  int tid = threadIdx.x;
  int ln = tid & 63, wvv = tid >> 6;
  int c0 = tid << 2;
  __shared__ float sred[36];

  float4 qv = *(const float4*)&q[((size_t)m << 10) + c0];
#pragma unroll
  for (int w = 0; w < 9; ++w) {
    int src = t + w - 8;
    float s = 0.f;
    if (src >= 0) {
      float4 kv = *(const float4*)&kk[((size_t)(m + w - 8) << 10) + c0];
      s = qv.x * kv.x + qv.y * kv.y + qv.z * kv.z + qv.w * kv.w;
    }
#pragma unroll
    for (int off = 32; off; off >>= 1) s += __shfl_xor(s, off);
    if (ln == 0) sred[w * 4 + wvv] = s;
  }
  __syncthreads();

  float p[9], mx = -3.4e38f;
#pragma unroll
  for (int w = 0; w < 9; ++w) {
    if (t + w - 8 >= 0) {
      float sc = (sred[w * 4] + sred[w * 4 + 1] + sred[w * 4 + 2] + sred[w * 4 + 3]) * 0.03125f;
      p[w] = sc; mx = fmaxf(mx, sc);
    } else p[w] = -3.4e38f;
  }
  float den = 0.f;
#pragma unroll
  for (int w = 0; w < 9; ++w) {
    float e = (t + w - 8 >= 0) ? exp2f(1.4426950408889634f * (p[w] - mx)) : 0.f;
    p[w] = e; den += e;
  }
  float inv = 1.f / den;
  float4 acc = {0.f, 0.f, 0.f, 0.f};
#pragma unroll
  for (int w = 0; w < 9; ++w) {
    if (t + w - 8 >= 0) {
      float4 vr = *(const float4*)&vv[((size_t)(m + w - 8) << 10) + c0];
      float pw = p[w] * inv;
      acc.x = fmaf(pw, vr.x, acc.x); acc.y = fmaf(pw, vr.y, acc.y);
      acc.z = fmaf(pw, vr.z, acc.z); acc.w = fmaf(pw, vr.w, acc.w);
    }
  }
  *(float4*)&o[((size_t)m << 10) + c0] = acc;
}

// ---------------- workspace layout (bytes) ----------------
constexpr size_t OFF_STATES = 0;                       // 4096*1024 f32 = 16.8 MB
constexpr size_t OFF_PREA   = 16777216;                // 4096*2048 f32 = 33.5 MB
constexpr size_t OFF_PREG   = 50331648;                // 16.8 MB
constexpr size_t OFF_PRER   = 67108864;                // 16.8 MB
constexpr size_t OFF_AG     = 83886080;                // 4*3072 f32
constexpr size_t OFF_HB     = 83935232;                // 4*1024 f32
constexpr size_t OFF_CNT    = 83951616;                // barrier tree: 9 x 512 B
constexpr size_t CNT_BYTES  = 4608;
constexpr size_t NEED_WS    = 83956224;

extern "C" void kernel_launch(void* const* d_in, const int* in_sizes, int n_in,
                              void* d_out, int out_size, void* d_ws, size_t ws_size,
                              hipStream_t stream) {
  const int*   x   = (const int*)d_in[0];
  const float* emb = (const float*)d_in[1];
  const float* W1c = (const float*)d_in[2];
  const float* b1c = (const float*)d_in[3];
  const float* W2c = (const float*)d_in[4];
  const float* b2c = (const float*)d_in[5];
  const float* Wg1 = (const float*)d_in[6];
  const float* bg1 = (const float*)d_in[7];
  const float* Wg2 = (const float*)d_in[8];
  const float* bg2 = (const float*)d_in[9];
  const float* Wr  = (const float*)d_in[10];
  const float* br  = (const float*)d_in[11];
  const float* Wk  = (const float*)d_in[12];
  const float* bk  = (const float*)d_in[13];
  const float* Wq  = (const float*)d_in[14];
  const float* bq  = (const float*)d_in[15];
  const float* Wv  = (const float*)d_in[16];
  const float* bv  = (const float*)d_in[17];
  const float* Wf  = (const float*)d_in[18];
  const float* bfv = (const float*)d_in[19];

  if (ws_size < NEED_WS) return;
  char* ws = (char*)d_ws;
  float* states = (float*)(ws + OFF_STATES);
  float* preA = (float*)(ws + OFF_PREA);
  float* preG = (float*)(ws + OFF_PREG);
  float* preR = (float*)(ws + OFF_PRER);
  float* agb  = (float*)(ws + OFF_AG);
  float* hbuf = (float*)(ws + OFF_HB);
  unsigned* barcnt = (unsigned*)(ws + OFF_CNT);

  dim3 blk(256);
  // zero the barrier tree (graph-capture-safe; replayed each graph launch)
  hipMemsetAsync(barcnt, 0, CNT_BYTES, stream);

  // precompute et-dependent parts (gathered-embedding GEMMs, K=512), biases folded in
  gemm_kernel<<<dim3(32, 64), blk, 0, stream>>>(nullptr, emb, x, W1c + (size_t)2048 * 2048, 2048,
                                                b1c, 1.f, preA, 4096, 2048, 512);
  gemm_kernel<<<dim3(16, 64), blk, 0, stream>>>(nullptr, emb, x, Wg1 + (size_t)2048 * 1024, 1024,
                                                bg1, 1.f, preG, 4096, 1024, 512);
  gemm_kernel<<<dim3(16, 64), blk, 0, stream>>>(nullptr, emb, x, Wr, 1024,
                                                br, 0.1f, preR, 4096, 1024, 512);

  // persistent cooperative recurrence (cooperative launch only for co-residency)
  hipFuncSetAttribute((const void*)recur_kernel,
                      hipFuncAttributeMaxDynamicSharedMemorySize, RC_LDS_BYTES);
  void* args[] = {(void*)&W1c, (void*)&Wg1, (void*)&W2c, (void*)&b2c, (void*)&Wg2, (void*)&bg2,
                  (void*)&preA, (void*)&preG, (void*)&preR,
                  (void*)&states, (void*)&agb, (void*)&hbuf, (void*)&barcnt};
  hipLaunchCooperativeKernel((const void*)recur_kernel, dim3(256), dim3(256),
                             args, RC_LDS_BYTES, stream);

  // q/k/v reuse the pre-buffers (no longer needed after the scan)
  float* qb = preA;
  float* kb = preA + 4194304;   // second 16.8 MB half of preA
  float* vb = preG;
  float* ab = preR;
  gemm_kernel<<<dim3(16, 64), blk, 0, stream>>>(states, nullptr, nullptr, Wq, 1024,
                                                bq, 1.f, qb, 4096, 1024, 1024);
  gemm_kernel<<<dim3(16, 64), blk, 0, stream>>>(states, nullptr, nullptr, Wk, 1024,
                                                bk, 1.f, kb, 4096, 1024, 1024);
  gemm_kernel<<<dim3(16, 64), blk, 0, stream>>>(states, nullptr, nullptr, Wv, 1024,
                                                bv, 1.f, vb, 4096, 1024, 1024);
  attn_kernel<<<dim3(4096), blk, 0, stream>>>(qb, kb, vb, ab);
  // final 268-GFLOP output GEMM
  gemm_kernel<<<dim3(500, 64), blk, 0, stream>>>(ab, nullptr, nullptr, Wf, 32000,
                                                 bfv, 1.f, (float*)d_out, 4096, 32000, 1024);
}

// Round 5
// 15503.000 us; speedup vs baseline: 1.5157x; 1.1522x over previous
//
#include <hip/hip_runtime.h>

typedef unsigned short ushort_t;

constexpr int TT = 1024;   // T;  B=4, H=1024, E=512, V=32000, W=8

// ---------------- helpers ----------------
__device__ __forceinline__ float blo(unsigned u) { return __uint_as_float(u << 16); }
__device__ __forceinline__ float bhi(unsigned u) { return __uint_as_float(u & 0xffff0000u); }
__device__ __forceinline__ ushort_t f2bf(float f) {
  unsigned u = __float_as_uint(f);
  unsigned r = (u + 0x7fffu + ((u >> 16) & 1u)) >> 16;  // RNE
  return (ushort_t)r;
}
__device__ __forceinline__ float tanh_fast(float x) {
  float ax = fabsf(x);
  float e = exp2f(ax * 2.885390081777927f);  // 2*log2(e)
  float r = 1.f - 2.f / (e + 1.f);
  return copysignf(r, x);
}

// Agent-scope (device-coherent, cross-XCD) scalar store (sc1 path).
__device__ __forceinline__ void st_agent(float* p, float v) {
  __hip_atomic_store(p, v, __ATOMIC_RELAXED, __HIP_MEMORY_SCOPE_AGENT);
}

// Batched coherent 16B loads: issue N dwordx4 sc0 sc1 loads, ONE vmcnt drain.
// (sc0=bypass L1, sc1=bypass per-XCD L2 -> read at coherent point/MALL.)
__device__ __forceinline__ void ldg_hb4(const float* p0, const float* p1,
                                        const float* p2, const float* p3,
                                        float4& r0, float4& r1, float4& r2, float4& r3)
{
  asm volatile(
    "global_load_dwordx4 %0, %4, off sc0 sc1\n\t"
    "global_load_dwordx4 %1, %5, off sc0 sc1\n\t"
    "global_load_dwordx4 %2, %6, off sc0 sc1\n\t"
    "global_load_dwordx4 %3, %7, off sc0 sc1\n\t"
    "s_waitcnt vmcnt(0)"
    : "=&v"(r0), "=&v"(r1), "=&v"(r2), "=&v"(r3)
    : "v"(p0), "v"(p1), "v"(p2), "v"(p3)
    : "memory");
}

// Phase-2 bundle: 4 gate chunks (gbase + i*1024B) + 8 cand chunks
// (cbase + i*1024B, i<8 via two bases). 12 loads in flight, one drain.
__device__ __forceinline__ void ldg_phase2(
    const float* gbase, const float* cbase,
    float4& g0, float4& g1, float4& g2, float4& g3,
    float4& a0, float4& a1, float4& a2, float4& a3,
    float4& a4, float4& a5, float4& a6, float4& a7)
{
  const float* cbase2 = cbase + 1024;  // +4096 B
  asm volatile(
    "global_load_dwordx4 %0, %12, off sc0 sc1\n\t"
    "global_load_dwordx4 %1, %12, off offset:1024 sc0 sc1\n\t"
    "global_load_dwordx4 %2, %12, off offset:2048 sc0 sc1\n\t"
    "global_load_dwordx4 %3, %12, off offset:3072 sc0 sc1\n\t"
    "global_load_dwordx4 %4, %13, off sc0 sc1\n\t"
    "global_load_dwordx4 %5, %13, off offset:1024 sc0 sc1\n\t"
    "global_load_dwordx4 %6, %13, off offset:2048 sc0 sc1\n\t"
    "global_load_dwordx4 %7, %13, off offset:3072 sc0 sc1\n\t"
    "global_load_dwordx4 %8, %14, off sc0 sc1\n\t"
    "global_load_dwordx4 %9, %14, off offset:1024 sc0 sc1\n\t"
    "global_load_dwordx4 %10, %14, off offset:2048 sc0 sc1\n\t"
    "global_load_dwordx4 %11, %14, off offset:3072 sc0 sc1\n\t"
    "s_waitcnt vmcnt(0)"
    : "=&v"(g0), "=&v"(g1), "=&v"(g2), "=&v"(g3),
      "=&v"(a0), "=&v"(a1), "=&v"(a2), "=&v"(a3),
      "=&v"(a4), "=&v"(a5), "=&v"(a6), "=&v"(a7)
    : "v"(gbase), "v"(cbase), "v"(cbase2)
    : "memory");
}

// ---- flag-array grid barrier (no RMW chains) ----
// flags[bid] lives on its own 64B line (stride 16 u32). Arrive = ONE plain
// sc1 store of (idx+1) by thread 0 (fire-and-forget, parallel across blocks).
// Detect = thread tid polls block tid's flag; 256 pollers cover 256 producers
// in parallel; lanes exit divergently as their flag lands.
// Ordering: __syncthreads() drains each wave's vmcnt before s_barrier, so all
// of the block's sc1 data stores are complete (at the coherent point) before
// the flag store. Monotonic targets (idx+1, idx in [0,2048)) -> no ABA; '>='
// tolerates fast blocks being one barrier ahead (max skew 1 by induction).
__device__ __forceinline__ void gbar(unsigned* flags, int idx) {
  unsigned tgt = (unsigned)(idx + 1);
  __syncthreads();
  if (threadIdx.x == 0) {
    asm volatile("" ::: "memory");
    __hip_atomic_store(flags + ((size_t)blockIdx.x << 4), tgt,
                       __ATOMIC_RELAXED, __HIP_MEMORY_SCOPE_AGENT);
  }
  const unsigned* myf = flags + ((size_t)threadIdx.x << 4);
  while (__hip_atomic_load(myf, __ATOMIC_RELAXED, __HIP_MEMORY_SCOPE_AGENT) < tgt)
    __builtin_amdgcn_s_sleep(1);
  __syncthreads();
}

// ---------------- generic tiled f32 GEMM:  C = scale*(A@W + bias) ----------------
// A: f32 (M,K) row-major, or gathered rows gA[gidx[m]] when gidx != null.
// W: f32 (K,N) row-major, leading dim ldw. M,N multiples of 64; K multiple of 16.
__global__ __launch_bounds__(256) void gemm_kernel(
    const float* __restrict__ A, const float* __restrict__ gA, const int* __restrict__ gidx,
    const float* __restrict__ W, int ldw,
    const float* __restrict__ bias, float scale,
    float* __restrict__ C, int M, int N, int K)
{
  __shared__ float As[16][68];
  __shared__ float Ws[16][68];
  int tid = threadIdx.x;
  int m0 = blockIdx.y * 64, n0 = blockIdx.x * 64;
  int tx = tid & 15, ty = tid >> 4;

  int am = tid >> 2;            // A-tile row 0..63
  int ak = (tid & 3) << 2;      // A-tile k  0,4,8,12
  int wk = tid >> 4;            // W-tile k  0..15
  int wn = (tid & 15) << 2;     // W-tile n  0..60
  int arow = m0 + am;
  const float* arow_p = (gidx != nullptr) ? &gA[(size_t)gidx[arow] * K] : &A[(size_t)arow * K];

  float acc[4][4];
#pragma unroll
  for (int i = 0; i < 4; ++i)
#pragma unroll
    for (int j = 0; j < 4; ++j) acc[i][j] = 0.f;

  for (int k0 = 0; k0 < K; k0 += 16) {
    float4 av = *(const float4*)&arow_p[k0 + ak];
    As[ak + 0][am] = av.x; As[ak + 1][am] = av.y;
    As[ak + 2][am] = av.z; As[ak + 3][am] = av.w;

    float4 wv = *(const float4*)&W[(size_t)(k0 + wk) * ldw + n0 + wn];
    Ws[wk][wn + 0] = wv.x; Ws[wk][wn + 1] = wv.y;
    Ws[wk][wn + 2] = wv.z; Ws[wk][wn + 3] = wv.w;
    __syncthreads();

#pragma unroll
    for (int kk = 0; kk < 16; ++kk) {
      float4 a4 = *(const float4*)&As[kk][ty << 2];
      float4 w4 = *(const float4*)&Ws[kk][tx << 2];
      float a_[4] = {a4.x, a4.y, a4.z, a4.w};
      float w_[4] = {w4.x, w4.y, w4.z, w4.w};
#pragma unroll
      for (int i = 0; i < 4; ++i)
#pragma unroll
        for (int j = 0; j < 4; ++j) acc[i][j] = fmaf(a_[i], w_[j], acc[i][j]);
    }
    __syncthreads();
  }

  int mbase = m0 + (ty << 2), nbase = n0 + (tx << 2);
  float bv4[4];
#pragma unroll
  for (int j = 0; j < 4; ++j) bv4[j] = bias[nbase + j];
#pragma unroll
  for (int i = 0; i < 4; ++i) {
    size_t ro = (size_t)(mbase + i) * N + nbase;
    float4 o;
    o.x = scale * (acc[i][0] + bv4[0]);
    o.y = scale * (acc[i][1] + bv4[1]);
    o.z = scale * (acc[i][2] + bv4[2]);
    o.w = scale * (acc[i][3] + bv4[3]);
    *(float4*)&C[ro] = o;
  }
}

// ---------------- persistent cooperative recurrence ----------------
// 256 blocks x 256 threads, 1 block/CU (100.6 KB LDS).
// Block bid owns stage-1 cols [bid*12, bid*12+12) of [a(2048)|g(1024)] and
// stage-2 cand cols [bid*4, +4). W1/W2/Wg2 bf16 in LDS; hn ping-pong in f32 LDS.
// Cross-block data (ag, hbuf): sc1 stores + batched dwordx4 sc0/sc1 loads.
// Sync: flag-array gbar() (parallel stores, parallel polls), 2 per step.

constexpr int LDS_W1  = 0;        // ushort[12*2048] = 49152
constexpr int LDS_W2  = 49152;    // ushort[ 4*2048] = 16384
constexpr int LDS_WG2 = 65536;    // ushort[1024]    =  2048
constexpr int LDS_HN  = 67584;    // float [2*4*1024]= 32768
constexpr int LDS_RED = 100352;   // float [64]      =   256
constexpr int LDS_B2  = 100608;   // float [4]       =    16
constexpr int RC_LDS_BYTES = 100624;

__global__ __launch_bounds__(256) void recur_kernel(
    const float* __restrict__ W1c, const float* __restrict__ Wg1,
    const float* __restrict__ W2c, const float* __restrict__ b2c,
    const float* __restrict__ Wg2, const float* __restrict__ bg2,
    const float* __restrict__ preA, const float* __restrict__ preG,
    const float* __restrict__ preR,
    float* __restrict__ states, float* __restrict__ ag,
    float* __restrict__ hbuf, unsigned* __restrict__ barcnt)
{
  extern __shared__ char lds[];
  ushort_t* w1   = (ushort_t*)(lds + LDS_W1);   // [c][k] c<12, k<2048
  ushort_t* w2   = (ushort_t*)(lds + LDS_W2);   // [c][k] c<4
  ushort_t* wg2l = (ushort_t*)(lds + LDS_WG2);
  float*    hnf  = (float*)(lds + LDS_HN);      // [sel][b][k] ping-pong hn(t-1)/hn(t-2)
  float*    red  = (float*)(lds + LDS_RED);
  float*    b2l  = (float*)(lds + LDS_B2);

  int tid = threadIdx.x, bid = blockIdx.x;
  int ln = tid & 63, wv = tid >> 6;  // wave index = batch b
  int j0 = bid * 12, j2 = bid << 2;

  // ---- init: zero hn, stage weights (f32 -> bf16) into LDS ----
  for (int i = tid; i < 8192; i += 256) hnf[i] = 0.f;
  for (int i = tid; i < 12 * 2048; i += 256) {
    int c = i % 12, k = i / 12, j = j0 + c;
    float v = (j < 2048) ? W1c[(size_t)k * 2048 + j]
                         : Wg1[(size_t)k * 1024 + (j - 2048)];
    w1[c * 2048 + k] = f2bf(v);
  }
  for (int i = tid; i < 4 * 2048; i += 256) {
    int c = i & 3, k = i >> 2;
    w2[c * 2048 + k] = f2bf(W2c[(size_t)k * 1024 + j2 + c]);
  }
  for (int i = tid; i < 1024; i += 256) wg2l[i] = f2bf(Wg2[i]);
  if (tid < 4) b2l[tid] = b2c[j2 + tid];
  float bg2v = bg2[0];
  __syncthreads();

  int p = 0;

  for (int t = 0; t <= TT; ++t) {
    // ---- fused LayerNorm of h(t-1): every block, redundant ----
    if (t > 0) {
      float4 xv[4]; float mu_[4], rs_[4];
      ldg_hb4(&hbuf[(0 << 10) + (tid << 2)], &hbuf[(1 << 10) + (tid << 2)],
              &hbuf[(2 << 10) + (tid << 2)], &hbuf[(3 << 10) + (tid << 2)],
              xv[0], xv[1], xv[2], xv[3]);
#pragma unroll
      for (int b = 0; b < 4; ++b) {
        float s  = xv[b].x + xv[b].y + xv[b].z + xv[b].w;
        float s2 = xv[b].x * xv[b].x + xv[b].y * xv[b].y + xv[b].z * xv[b].z + xv[b].w * xv[b].w;
#pragma unroll
        for (int off = 32; off; off >>= 1) { s += __shfl_xor(s, off); s2 += __shfl_xor(s2, off); }
        if (ln == 0) { red[(wv << 3) + (b << 1)] = s; red[(wv << 3) + (b << 1) + 1] = s2; }
      }
      __syncthreads();
#pragma unroll
      for (int b = 0; b < 4; ++b) {
        float s  = red[(b << 1)] + red[8 + (b << 1)] + red[16 + (b << 1)] + red[24 + (b << 1)];
        float s2 = red[(b << 1) + 1] + red[8 + (b << 1) + 1] + red[16 + (b << 1) + 1] + red[24 + (b << 1) + 1];
        float mu = s * (1.f / 1024.f);
        float var = s2 * (1.f / 1024.f) - mu * mu;
        mu_[b] = mu; rs_[b] = rsqrtf(var + 1e-5f);
      }
      int np = p ^ 1;
#pragma unroll
      for (int b = 0; b < 4; ++b) {
        float4 xn;
        xn.x = (xv[b].x - mu_[b]) * rs_[b];
        xn.y = (xv[b].y - mu_[b]) * rs_[b];
        xn.z = (xv[b].z - mu_[b]) * rs_[b];
        xn.w = (xv[b].w - mu_[b]) * rs_[b];
        *(float4*)&hnf[np * 4096 + (b << 10) + (tid << 2)] = xn;
        if (tid == bid)  // thread bid's slice == this block's states slice
          *(float4*)&states[((size_t)((b << 10) + (t - 1)) << 10) + (bid << 2)] = xn;
      }
      p = np;
      __syncthreads();
    }
    if (t == TT) break;

    // ---- phase 1: this block's 12 a/g columns.  K-vec = [hn(t-1) | hn(t-2)] ----
    {
      int b = wv;
      const float* pA = preA + ((size_t)((b << 10) + t) << 11);  // row * 2048
      const float* pG = preG + ((size_t)((b << 10) + t) << 10);  // row * 1024
      // hoisted pre load: issues early, hides under the k-loop
      float pre = 0.f;
      if (ln < 12) {
        int j = j0 + ln;
        pre = (j < 2048) ? pA[j] : pG[j - 2048];
      }
      float acc[12];
#pragma unroll
      for (int c = 0; c < 12; ++c) acc[c] = 0.f;
      for (int k0 = 0; k0 < 2048; k0 += 256) {
        int kk = k0 + (ln << 2);
        int sel = (k0 < 1024) ? p : (p ^ 1);
        float4 hv = *(const float4*)&hnf[sel * 4096 + (b << 10) + (kk & 1023)];
#pragma unroll
        for (int c = 0; c < 12; ++c) {
          uint2 wq = *(const uint2*)&w1[c * 2048 + kk];
          float a = acc[c];
          a = fmaf(blo(wq.x), hv.x, a); a = fmaf(bhi(wq.x), hv.y, a);
          a = fmaf(blo(wq.y), hv.z, a); a = fmaf(bhi(wq.y), hv.w, a);
          acc[c] = a;
        }
      }
#pragma unroll
      for (int c = 0; c < 12; ++c) {
        float v = acc[c];
#pragma unroll
        for (int off = 32; off; off >>= 1) v += __shfl_xor(v, off);
        acc[c] = v;
      }
      if (ln < 12) {
        float v = acc[0];
#pragma unroll
        for (int c = 1; c < 12; ++c) if (ln == c) v = acc[c];
        st_agent(&ag[b * 3072 + j0 + ln], v + pre);
      }
    }
    gbar(barcnt, 2 * t);

    // ---- phase 2: gate (redundant per block) + 4 cand columns + h ----
    {
      int b = wv;
      const float* agv = ag + b * 3072;
      // hoisted preR load
      float pr = 0.f;
      if (ln < 4) pr = preR[((size_t)((b << 10) + t) << 10) + j2 + ln];

      float4 g0, g1, g2, g3, a0, a1, a2, a3, a4, a5, a6, a7;
      ldg_phase2(agv + 2048 + (ln << 2), agv + (ln << 2),
                 g0, g1, g2, g3, a0, a1, a2, a3, a4, a5, a6, a7);
      float4 gv_[4] = {g0, g1, g2, g3};
      float4 av_[8] = {a0, a1, a2, a3, a4, a5, a6, a7};

      float gs = 0.f;
#pragma unroll
      for (int i = 0; i < 4; ++i) {
        int gi = ((i << 6) + ln) << 2;
        uint2 wq = *(const uint2*)&wg2l[gi];
        gs = fmaf(tanh_fast(gv_[i].x), blo(wq.x), gs);
        gs = fmaf(tanh_fast(gv_[i].y), bhi(wq.x), gs);
        gs = fmaf(tanh_fast(gv_[i].z), blo(wq.y), gs);
        gs = fmaf(tanh_fast(gv_[i].w), bhi(wq.y), gs);
      }
#pragma unroll
      for (int off = 32; off; off >>= 1) gs += __shfl_xor(gs, off);
      float gate = 1.f / (1.f + exp2f(-1.4426950408889634f * (gs + bg2v)));

      float acc2[4] = {0.f, 0.f, 0.f, 0.f};
#pragma unroll
      for (int i = 0; i < 8; ++i) {
        int kk = (i << 8) + (ln << 2);
        float ax = fmaxf(av_[i].x, 0.f), ay = fmaxf(av_[i].y, 0.f);
        float az = fmaxf(av_[i].z, 0.f), aw = fmaxf(av_[i].w, 0.f);
#pragma unroll
        for (int c = 0; c < 4; ++c) {
          uint2 wq = *(const uint2*)&w2[c * 2048 + kk];
          float a = acc2[c];
          a = fmaf(blo(wq.x), ax, a); a = fmaf(bhi(wq.x), ay, a);
          a = fmaf(blo(wq.y), az, a); a = fmaf(bhi(wq.y), aw, a);
          acc2[c] = a;
        }
      }
#pragma unroll
      for (int c = 0; c < 4; ++c) {
        float v = acc2[c];
#pragma unroll
        for (int off = 32; off; off >>= 1) v += __shfl_xor(v, off);
        acc2[c] = v;
      }
      if (ln < 4) {
        float cand = acc2[0];
#pragma unroll
        for (int c = 1; c < 4; ++c) if (ln == c) cand = acc2[c];
        cand += b2l[ln];
        float h1v = hnf[p * 4096 + (b << 10) + j2 + ln];   // h1 = hn(t-1)
        st_agent(&hbuf[(b << 10) + j2 + ln], h1v + gate * cand + pr);
      }
    }
    gbar(barcnt, 2 * t + 1);
  }
}

// ---------------- windowed attention (W=8, 9 taps) ----------------
__global__ __launch_bounds__(256) void attn_kernel(
    const float* __restrict__ q, const float* __restrict__ kk,
    const float* __restrict__ vv, float* __restrict__ o)
{
  int m = blockIdx.x;           // b*T + t
  int t = m & 1023;
  int tid = threadIdx.x;
  int ln = tid & 63, wvv = tid >> 6;
  int c0 = tid << 2;
  __shared__ float sred[36];

  float4 qv = *(const float4*)&q[((size_t)m << 10) + c0];
#pragma unroll
  for (int w = 0; w < 9; ++w) {
    int src = t + w - 8;
    float s = 0.f;
    if (src >= 0) {
      float4 kv = *(const float4*)&kk[((size_t)(m + w - 8) << 10) + c0];
      s = qv.x * kv.x + qv.y * kv.y + qv.z * kv.z + qv.w * kv.w;
    }
#pragma unroll
    for (int off = 32; off; off >>= 1) s += __shfl_xor(s, off);
    if (ln == 0) sred[w * 4 + wvv] = s;
  }
  __syncthreads();

  float p[9], mx = -3.4e38f;
#pragma unroll
  for (int w = 0; w < 9; ++w) {
    if (t + w - 8 >= 0) {
      float sc = (sred[w * 4] + sred[w * 4 + 1] + sred[w * 4 + 2] + sred[w * 4 + 3]) * 0.03125f;
      p[w] = sc; mx = fmaxf(mx, sc);
    } else p[w] = -3.4e38f;
  }
  float den = 0.f;
#pragma unroll
  for (int w = 0; w < 9; ++w) {
    float e = (t + w - 8 >= 0) ? exp2f(1.4426950408889634f * (p[w] - mx)) : 0.f;
    p[w] = e; den += e;
  }
  float inv = 1.f / den;
  float4 acc = {0.f, 0.f, 0.f, 0.f};
#pragma unroll
  for (int w = 0; w < 9; ++w) {
    if (t + w - 8 >= 0) {
      float4 vr = *(const float4*)&vv[((size_t)(m + w - 8) << 10) + c0];
      float pw = p[w] * inv;
      acc.x = fmaf(pw, vr.x, acc.x); acc.y = fmaf(pw, vr.y, acc.y);
      acc.z = fmaf(pw, vr.z, acc.z); acc.w = fmaf(pw, vr.w, acc.w);
    }
  }
  *(float4*)&o[((size_t)m << 10) + c0] = acc;
}

// ---------------- workspace layout (bytes) ----------------
constexpr size_t OFF_STATES = 0;                       // 4096*1024 f32 = 16.8 MB
constexpr size_t OFF_PREA   = 16777216;                // 4096*2048 f32 = 33.5 MB
constexpr size_t OFF_PREG   = 50331648;                // 16.8 MB
constexpr size_t OFF_PRER   = 67108864;                // 16.8 MB
constexpr size_t OFF_AG     = 83886080;                // 4*3072 f32
constexpr size_t OFF_HB     = 83935232;                // 4*1024 f32
constexpr size_t OFF_CNT    = 83951616;                // flag array: 256 x 64 B
constexpr size_t CNT_BYTES  = 16384;
constexpr size_t NEED_WS    = 83968000;

extern "C" void kernel_launch(void* const* d_in, const int* in_sizes, int n_in,
                              void* d_out, int out_size, void* d_ws, size_t ws_size,
                              hipStream_t stream) {
  const int*   x   = (const int*)d_in[0];
  const float* emb = (const float*)d_in[1];
  const float* W1c = (const float*)d_in[2];
  const float* b1c = (const float*)d_in[3];
  const float* W2c = (const float*)d_in[4];
  const float* b2c = (const float*)d_in[5];
  const float* Wg1 = (const float*)d_in[6];
  const float* bg1 = (const float*)d_in[7];
  const float* Wg2 = (const float*)d_in[8];
  const float* bg2 = (const float*)d_in[9];
  const float* Wr  = (const float*)d_in[10];
  const float* br  = (const float*)d_in[11];
  const float* Wk  = (const float*)d_in[12];
  const float* bk  = (const float*)d_in[13];
  const float* Wq  = (const float*)d_in[14];
  const float* bq  = (const float*)d_in[15];
  const float* Wv  = (const float*)d_in[16];
  const float* bv  = (const float*)d_in[17];
  const float* Wf  = (const float*)d_in[18];
  const float* bfv = (const float*)d_in[19];

  if (ws_size < NEED_WS) return;
  char* ws = (char*)d_ws;
  float* states = (float*)(ws + OFF_STATES);
  float* preA = (float*)(ws + OFF_PREA);
  float* preG = (float*)(ws + OFF_PREG);
  float* preR = (float*)(ws + OFF_PRER);
  float* agb  = (float*)(ws + OFF_AG);
  float* hbuf = (float*)(ws + OFF_HB);
  unsigned* barcnt = (unsigned*)(ws + OFF_CNT);

  dim3 blk(256);
  // zero the flag array (graph-capture-safe; replayed each graph launch)
  hipMemsetAsync(barcnt, 0, CNT_BYTES, stream);

  // precompute et-dependent parts (gathered-embedding GEMMs, K=512), biases folded in
  gemm_kernel<<<dim3(32, 64), blk, 0, stream>>>(nullptr, emb, x, W1c + (size_t)2048 * 2048, 2048,
                                                b1c, 1.f, preA, 4096, 2048, 512);
  gemm_kernel<<<dim3(16, 64), blk, 0, stream>>>(nullptr, emb, x, Wg1 + (size_t)2048 * 1024, 1024,
                                                bg1, 1.f, preG, 4096, 1024, 512);
  gemm_kernel<<<dim3(16, 64), blk, 0, stream>>>(nullptr, emb, x, Wr, 1024,
                                                br, 0.1f, preR, 4096, 1024, 512);

  // persistent cooperative recurrence (cooperative launch only for co-residency)
  hipFuncSetAttribute((const void*)recur_kernel,
                      hipFuncAttributeMaxDynamicSharedMemorySize, RC_LDS_BYTES);
  void* args[] = {(void*)&W1c, (void*)&Wg1, (void*)&W2c, (void*)&b2c, (void*)&Wg2, (void*)&bg2,
                  (void*)&preA, (void*)&preG, (void*)&preR,
                  (void*)&states, (void*)&agb, (void*)&hbuf, (void*)&barcnt};
  hipLaunchCooperativeKernel((const void*)recur_kernel, dim3(256), dim3(256),
                             args, RC_LDS_BYTES, stream);

  // q/k/v reuse the pre-buffers (no longer needed after the scan)
  float* qb = preA;
  float* kb = preA + 4194304;   // second 16.8 MB half of preA
  float* vb = preG;
  float* ab = preR;
  gemm_kernel<<<dim3(16, 64), blk, 0, stream>>>(states, nullptr, nullptr, Wq, 1024,
                                                bq, 1.f, qb, 4096, 1024, 1024);
  gemm_kernel<<<dim3(16, 64), blk, 0, stream>>>(states, nullptr, nullptr, Wk, 1024,
                                                bk, 1.f, kb, 4096, 1024, 1024);
  gemm_kernel<<<dim3(16, 64), blk, 0, stream>>>(states, nullptr, nullptr, Wv, 1024,
                                                bv, 1.f, vb, 4096, 1024, 1024);
  attn_kernel<<<dim3(4096), blk, 0, stream>>>(qb, kb, vb, ab);
  // final 268-GFLOP output GEMM
  gemm_kernel<<<dim3(500, 64), blk, 0, stream>>>(ab, nullptr, nullptr, Wf, 32000,
                                                 bfv, 1.f, (float*)d_out, 4096, 32000, 1024);
}

// Round 6
// 14130.487 us; speedup vs baseline: 1.6629x; 1.0971x over previous
//
#include <hip/hip_runtime.h>

typedef unsigned short ushort_t;
typedef __attribute__((ext_vector_type(8))) short bf16x8;
typedef __attribute__((ext_vector_type(4))) float f32x4;

constexpr int TT = 1024;   // T;  B=4, H=1024, E=512, V=32000, W=8

// ---------------- helpers ----------------
__device__ __forceinline__ float blo(unsigned u) { return __uint_as_float(u << 16); }
__device__ __forceinline__ float bhi(unsigned u) { return __uint_as_float(u & 0xffff0000u); }
__device__ __forceinline__ ushort_t f2bf(float f) {
  unsigned u = __float_as_uint(f);
  unsigned r = (u + 0x7fffu + ((u >> 16) & 1u)) >> 16;  // RNE
  return (ushort_t)r;
}
__device__ __forceinline__ float tanh_fast(float x) {
  float ax = fabsf(x);
  float e = exp2f(ax * 2.885390081777927f);  // 2*log2(e)
  float r = 1.f - 2.f / (e + 1.f);
  return copysignf(r, x);
}

// Agent-scope (device-coherent, cross-XCD) scalar store (sc1 path).
__device__ __forceinline__ void st_agent(float* p, float v) {
  __hip_atomic_store(p, v, __ATOMIC_RELAXED, __HIP_MEMORY_SCOPE_AGENT);
}

// Batched coherent 16B loads: issue N dwordx4 sc0 sc1 loads, ONE vmcnt drain.
__device__ __forceinline__ void ldg_hb4(const float* p0, const float* p1,
                                        const float* p2, const float* p3,
                                        float4& r0, float4& r1, float4& r2, float4& r3)
{
  asm volatile(
    "global_load_dwordx4 %0, %4, off sc0 sc1\n\t"
    "global_load_dwordx4 %1, %5, off sc0 sc1\n\t"
    "global_load_dwordx4 %2, %6, off sc0 sc1\n\t"
    "global_load_dwordx4 %3, %7, off sc0 sc1\n\t"
    "s_waitcnt vmcnt(0)"
    : "=&v"(r0), "=&v"(r1), "=&v"(r2), "=&v"(r3)
    : "v"(p0), "v"(p1), "v"(p2), "v"(p3)
    : "memory");
}

// Phase-2 bundle: 4 gate chunks + 8 cand chunks. 12 loads in flight, one drain.
__device__ __forceinline__ void ldg_phase2(
    const float* gbase, const float* cbase,
    float4& g0, float4& g1, float4& g2, float4& g3,
    float4& a0, float4& a1, float4& a2, float4& a3,
    float4& a4, float4& a5, float4& a6, float4& a7)
{
  const float* cbase2 = cbase + 1024;  // +4096 B
  asm volatile(
    "global_load_dwordx4 %0, %12, off sc0 sc1\n\t"
    "global_load_dwordx4 %1, %12, off offset:1024 sc0 sc1\n\t"
    "global_load_dwordx4 %2, %12, off offset:2048 sc0 sc1\n\t"
    "global_load_dwordx4 %3, %12, off offset:3072 sc0 sc1\n\t"
    "global_load_dwordx4 %4, %13, off sc0 sc1\n\t"
    "global_load_dwordx4 %5, %13, off offset:1024 sc0 sc1\n\t"
    "global_load_dwordx4 %6, %13, off offset:2048 sc0 sc1\n\t"
    "global_load_dwordx4 %7, %13, off offset:3072 sc0 sc1\n\t"
    "global_load_dwordx4 %8, %14, off sc0 sc1\n\t"
    "global_load_dwordx4 %9, %14, off offset:1024 sc0 sc1\n\t"
    "global_load_dwordx4 %10, %14, off offset:2048 sc0 sc1\n\t"
    "global_load_dwordx4 %11, %14, off offset:3072 sc0 sc1\n\t"
    "s_waitcnt vmcnt(0)"
    : "=&v"(g0), "=&v"(g1), "=&v"(g2), "=&v"(g3),
      "=&v"(a0), "=&v"(a1), "=&v"(a2), "=&v"(a3),
      "=&v"(a4), "=&v"(a5), "=&v"(a6), "=&v"(a7)
    : "v"(gbase), "v"(cbase), "v"(cbase2)
    : "memory");
}

// ---- flag-array grid barrier (no RMW chains) ----
__device__ __forceinline__ void gbar(unsigned* flags, int idx) {
  unsigned tgt = (unsigned)(idx + 1);
  __syncthreads();
  if (threadIdx.x == 0) {
    asm volatile("" ::: "memory");
    __hip_atomic_store(flags + ((size_t)blockIdx.x << 4), tgt,
                       __ATOMIC_RELAXED, __HIP_MEMORY_SCOPE_AGENT);
  }
  const unsigned* myf = flags + ((size_t)threadIdx.x << 4);
  while (__hip_atomic_load(myf, __ATOMIC_RELAXED, __HIP_MEMORY_SCOPE_AGENT) < tgt)
    __builtin_amdgcn_s_sleep(1);
  __syncthreads();
}

// ---------------- generic tiled f32 GEMM:  C = scale*(A@W + bias) ----------------
__global__ __launch_bounds__(256) void gemm_kernel(
    const float* __restrict__ A, const float* __restrict__ gA, const int* __restrict__ gidx,
    const float* __restrict__ W, int ldw,
    const float* __restrict__ bias, float scale,
    float* __restrict__ C, int M, int N, int K)
{
  __shared__ float As[16][68];
  __shared__ float Ws[16][68];
  int tid = threadIdx.x;
  int m0 = blockIdx.y * 64, n0 = blockIdx.x * 64;
  int tx = tid & 15, ty = tid >> 4;

  int am = tid >> 2;            // A-tile row 0..63
  int ak = (tid & 3) << 2;      // A-tile k  0,4,8,12
  int wk = tid >> 4;            // W-tile k  0..15
  int wn = (tid & 15) << 2;     // W-tile n  0..60
  int arow = m0 + am;
  const float* arow_p = (gidx != nullptr) ? &gA[(size_t)gidx[arow] * K] : &A[(size_t)arow * K];

  float acc[4][4];
#pragma unroll
  for (int i = 0; i < 4; ++i)
#pragma unroll
    for (int j = 0; j < 4; ++j) acc[i][j] = 0.f;

  for (int k0 = 0; k0 < K; k0 += 16) {
    float4 av = *(const float4*)&arow_p[k0 + ak];
    As[ak + 0][am] = av.x; As[ak + 1][am] = av.y;
    As[ak + 2][am] = av.z; As[ak + 3][am] = av.w;

    float4 wv = *(const float4*)&W[(size_t)(k0 + wk) * ldw + n0 + wn];
    Ws[wk][wn + 0] = wv.x; Ws[wk][wn + 1] = wv.y;
    Ws[wk][wn + 2] = wv.z; Ws[wk][wn + 3] = wv.w;
    __syncthreads();

#pragma unroll
    for (int kk = 0; kk < 16; ++kk) {
      float4 a4 = *(const float4*)&As[kk][ty << 2];
      float4 w4 = *(const float4*)&Ws[kk][tx << 2];
      float a_[4] = {a4.x, a4.y, a4.z, a4.w};
      float w_[4] = {w4.x, w4.y, w4.z, w4.w};
#pragma unroll
      for (int i = 0; i < 4; ++i)
#pragma unroll
        for (int j = 0; j < 4; ++j) acc[i][j] = fmaf(a_[i], w_[j], acc[i][j]);
    }
    __syncthreads();
  }

  int mbase = m0 + (ty << 2), nbase = n0 + (tx << 2);
  float bv4[4];
#pragma unroll
  for (int j = 0; j < 4; ++j) bv4[j] = bias[nbase + j];
#pragma unroll
  for (int i = 0; i < 4; ++i) {
    size_t ro = (size_t)(mbase + i) * N + nbase;
    float4 o;
    o.x = scale * (acc[i][0] + bv4[0]);
    o.y = scale * (acc[i][1] + bv4[1]);
    o.z = scale * (acc[i][2] + bv4[2]);
    o.w = scale * (acc[i][3] + bv4[3]);
    *(float4*)&C[ro] = o;
  }
}

// ---------------- bf16x3 MFMA GEMM for the 268-GF output projection ----------------
// out[4096][32000] = A[4096][1024] @ W[1024][32000] + bias, f32-accurate via
// split a=ah+al, w=wh+wl (bf16): acc += ah*wh + ah*wl + al*wh (lo*lo ~2^-18 dropped).
// 128x128 tile, BK=32, 4 waves in 2x2 quadrants, 4x4 16x16x32 MFMA frags each.
// Verified layouts (learn_hip m89/m91): C/D col=lane&15 row=(lane>>4)*4+reg;
// A row=lane&15 k=8*(lane>>4)+j; B col=lane&15 k=8*(lane>>4)+j.
// LDS: A row-major [m][k], W transposed to n-major [n][k] -> frag = 1 ds_read_b128.
// +8-ushort row pad kills the 8-way bank conflict (stride 40 -> 2-way).
__global__ __launch_bounds__(256, 2) void mfma_gemm(
    const float* __restrict__ A, const float* __restrict__ W,
    const float* __restrict__ bias, float* __restrict__ C)
{
  __shared__ ushort_t Ah[128][40], Al[128][40], Bh[128][40], Bl[128][40];
  int tid = threadIdx.x;
  int bid = blockIdx.x;
  int mb = bid & 31, nb = bid >> 5;      // m fast: n-panel-major execution (A stays MALL-hot)
  int m0 = mb << 7, n0 = nb << 7;
  int l = tid & 63;
  int wv = tid >> 6;
  int wr = wv >> 1, wc = wv & 1;         // wave quadrant (64x64)
  int lr = l & 15, lg = l >> 4;

  f32x4 acc[4][4];
#pragma unroll
  for (int i = 0; i < 4; ++i)
#pragma unroll
    for (int j = 0; j < 4; ++j) acc[i][j] = (f32x4){0.f, 0.f, 0.f, 0.f};

  for (int k0 = 0; k0 < 1024; k0 += 32) {
    __syncthreads();   // protect LDS vs previous iteration's reads
    // ---- stage A tile 128x32 (row-major) ----
#pragma unroll
    for (int r = 0; r < 4; ++r) {
      int q = (r << 8) + tid;
      int row = q >> 3, kq = q & 7;
      float4 v = *(const float4*)&A[(size_t)(m0 + row) * 1024 + k0 + (kq << 2)];
      float vv[4] = {v.x, v.y, v.z, v.w};
      unsigned hw0, hw1, lw0, lw1;
      {
        ushort_t h0 = f2bf(vv[0]), h1 = f2bf(vv[1]), h2 = f2bf(vv[2]), h3 = f2bf(vv[3]);
        ushort_t l0 = f2bf(vv[0] - blo(h0)), l1 = f2bf(vv[1] - blo(h1));
        ushort_t l2 = f2bf(vv[2] - blo(h2)), l3 = f2bf(vv[3] - blo(h3));
        hw0 = (unsigned)h0 | ((unsigned)h1 << 16); hw1 = (unsigned)h2 | ((unsigned)h3 << 16);
        lw0 = (unsigned)l0 | ((unsigned)l1 << 16); lw1 = (unsigned)l2 | ((unsigned)l3 << 16);
      }
      *(uint2*)&Ah[row][kq << 2] = make_uint2(hw0, hw1);
      *(uint2*)&Al[row][kq << 2] = make_uint2(lw0, lw1);
    }
    // ---- stage W tile 32x128, transposed into [n][k] ----
#pragma unroll
    for (int r = 0; r < 4; ++r) {
      int q = (r << 8) + tid;
      int wrow = q >> 5, nq = q & 31;
      float4 v = *(const float4*)&W[(size_t)(k0 + wrow) * 32000 + n0 + (nq << 2)];
      float vv[4] = {v.x, v.y, v.z, v.w};
#pragma unroll
      for (int e = 0; e < 4; ++e) {
        ushort_t h = f2bf(vv[e]);
        Bh[(nq << 2) + e][wrow] = h;
        Bl[(nq << 2) + e][wrow] = f2bf(vv[e] - blo(h));
      }
    }
    __syncthreads();

    // ---- compute: hoist 8 B-frags, loop A row-blocks ----
    bf16x8 bh[4], bl[4];
#pragma unroll
    for (int j = 0; j < 4; ++j) {
      int nrow = (wc << 6) + (j << 4) + lr;
      bh[j] = *(const bf16x8*)&Bh[nrow][lg << 3];
      bl[j] = *(const bf16x8*)&Bl[nrow][lg << 3];
    }
#pragma unroll
    for (int i = 0; i < 4; ++i) {
      int arow = (wr << 6) + (i << 4) + lr;
      bf16x8 ah = *(const bf16x8*)&Ah[arow][lg << 3];
      bf16x8 al = *(const bf16x8*)&Al[arow][lg << 3];
#pragma unroll
      for (int j = 0; j < 4; ++j) {
        acc[i][j] = __builtin_amdgcn_mfma_f32_16x16x32_bf16(ah, bh[j], acc[i][j], 0, 0, 0);
        acc[i][j] = __builtin_amdgcn_mfma_f32_16x16x32_bf16(ah, bl[j], acc[i][j], 0, 0, 0);
        acc[i][j] = __builtin_amdgcn_mfma_f32_16x16x32_bf16(al, bh[j], acc[i][j], 0, 0, 0);
      }
    }
  }

  // ---- epilogue: +bias, f32 store.  C row = m0+wr*64+i*16+(lg*4+r), col = n0+wc*64+j*16+lr
#pragma unroll
  for (int j = 0; j < 4; ++j) {
    int n = n0 + (wc << 6) + (j << 4) + lr;
    float bv = bias[n];
#pragma unroll
    for (int i = 0; i < 4; ++i) {
      int mbase = m0 + (wr << 6) + (i << 4) + (lg << 2);
#pragma unroll
      for (int r = 0; r < 4; ++r)
        C[(size_t)(mbase + r) * 32000 + n] = acc[i][j][r] + bv;
    }
  }
}

// ---------------- persistent cooperative recurrence (unchanged from R5) ----------------
constexpr int LDS_W1  = 0;        // ushort[12*2048] = 49152
constexpr int LDS_W2  = 49152;    // ushort[ 4*2048] = 16384
constexpr int LDS_WG2 = 65536;    // ushort[1024]    =  2048
constexpr int LDS_HN  = 67584;    // float [2*4*1024]= 32768
constexpr int LDS_RED = 100352;   // float [64]      =   256
constexpr int LDS_B2  = 100608;   // float [4]       =    16
constexpr int RC_LDS_BYTES = 100624;

__global__ __launch_bounds__(256) void recur_kernel(
    const float* __restrict__ W1c, const float* __restrict__ Wg1,
    const float* __restrict__ W2c, const float* __restrict__ b2c,
    const float* __restrict__ Wg2, const float* __restrict__ bg2,
    const float* __restrict__ preA, const float* __restrict__ preG,
    const float* __restrict__ preR,
    float* __restrict__ states, float* __restrict__ ag,
    float* __restrict__ hbuf, unsigned* __restrict__ barcnt)
{
  extern __shared__ char lds[];
  ushort_t* w1   = (ushort_t*)(lds + LDS_W1);   // [c][k] c<12, k<2048
  ushort_t* w2   = (ushort_t*)(lds + LDS_W2);   // [c][k] c<4
  ushort_t* wg2l = (ushort_t*)(lds + LDS_WG2);
  float*    hnf  = (float*)(lds + LDS_HN);      // [sel][b][k] ping-pong hn(t-1)/hn(t-2)
  float*    red  = (float*)(lds + LDS_RED);
  float*    b2l  = (float*)(lds + LDS_B2);

  int tid = threadIdx.x, bid = blockIdx.x;
  int ln = tid & 63, wv = tid >> 6;  // wave index = batch b
  int j0 = bid * 12, j2 = bid << 2;

  for (int i = tid; i < 8192; i += 256) hnf[i] = 0.f;
  for (int i = tid; i < 12 * 2048; i += 256) {
    int c = i % 12, k = i / 12, j = j0 + c;
    float v = (j < 2048) ? W1c[(size_t)k * 2048 + j]
                         : Wg1[(size_t)k * 1024 + (j - 2048)];
    w1[c * 2048 + k] = f2bf(v);
  }
  for (int i = tid; i < 4 * 2048; i += 256) {
    int c = i & 3, k = i >> 2;
    w2[c * 2048 + k] = f2bf(W2c[(size_t)k * 1024 + j2 + c]);
  }
  for (int i = tid; i < 1024; i += 256) wg2l[i] = f2bf(Wg2[i]);
  if (tid < 4) b2l[tid] = b2c[j2 + tid];
  float bg2v = bg2[0];
  __syncthreads();

  int p = 0;

  for (int t = 0; t <= TT; ++t) {
    if (t > 0) {
      float4 xv[4]; float mu_[4], rs_[4];
      ldg_hb4(&hbuf[(0 << 10) + (tid << 2)], &hbuf[(1 << 10) + (tid << 2)],
              &hbuf[(2 << 10) + (tid << 2)], &hbuf[(3 << 10) + (tid << 2)],
              xv[0], xv[1], xv[2], xv[3]);
#pragma unroll
      for (int b = 0; b < 4; ++b) {
        float s  = xv[b].x + xv[b].y + xv[b].z + xv[b].w;
        float s2 = xv[b].x * xv[b].x + xv[b].y * xv[b].y + xv[b].z * xv[b].z + xv[b].w * xv[b].w;
#pragma unroll
        for (int off = 32; off; off >>= 1) { s += __shfl_xor(s, off); s2 += __shfl_xor(s2, off); }
        if (ln == 0) { red[(wv << 3) + (b << 1)] = s; red[(wv << 3) + (b << 1) + 1] = s2; }
      }
      __syncthreads();
#pragma unroll
      for (int b = 0; b < 4; ++b) {
        float s  = red[(b << 1)] + red[8 + (b << 1)] + red[16 + (b << 1)] + red[24 + (b << 1)];
        float s2 = red[(b << 1) + 1] + red[8 + (b << 1) + 1] + red[16 + (b << 1) + 1] + red[24 + (b << 1) + 1];
        float mu = s * (1.f / 1024.f);
        float var = s2 * (1.f / 1024.f) - mu * mu;
        mu_[b] = mu; rs_[b] = rsqrtf(var + 1e-5f);
      }
      int np = p ^ 1;
#pragma unroll
      for (int b = 0; b < 4; ++b) {
        float4 xn;
        xn.x = (xv[b].x - mu_[b]) * rs_[b];
        xn.y = (xv[b].y - mu_[b]) * rs_[b];
        xn.z = (xv[b].z - mu_[b]) * rs_[b];
        xn.w = (xv[b].w - mu_[b]) * rs_[b];
        *(float4*)&hnf[np * 4096 + (b << 10) + (tid << 2)] = xn;
        if (tid == bid)
          *(float4*)&states[((size_t)((b << 10) + (t - 1)) << 10) + (bid << 2)] = xn;
      }
      p = np;
      __syncthreads();
    }
    if (t == TT) break;

    {
      int b = wv;
      const float* pA = preA + ((size_t)((b << 10) + t) << 11);
      const float* pG = preG + ((size_t)((b << 10) + t) << 10);
      float pre = 0.f;
      if (ln < 12) {
        int j = j0 + ln;
        pre = (j < 2048) ? pA[j] : pG[j - 2048];
      }
      float acc[12];
#pragma unroll
      for (int c = 0; c < 12; ++c) acc[c] = 0.f;
      for (int k0 = 0; k0 < 2048; k0 += 256) {
        int kk = k0 + (ln << 2);
        int sel = (k0 < 1024) ? p : (p ^ 1);
        float4 hv = *(const float4*)&hnf[sel * 4096 + (b << 10) + (kk & 1023)];
#pragma unroll
        for (int c = 0; c < 12; ++c) {
          uint2 wq = *(const uint2*)&w1[c * 2048 + kk];
          float a = acc[c];
          a = fmaf(blo(wq.x), hv.x, a); a = fmaf(bhi(wq.x), hv.y, a);
          a = fmaf(blo(wq.y), hv.z, a); a = fmaf(bhi(wq.y), hv.w, a);
          acc[c] = a;
        }
      }
#pragma unroll
      for (int c = 0; c < 12; ++c) {
        float v = acc[c];
#pragma unroll
        for (int off = 32; off; off >>= 1) v += __shfl_xor(v, off);
        acc[c] = v;
      }
      if (ln < 12) {
        float v = acc[0];
#pragma unroll
        for (int c = 1; c < 12; ++c) if (ln == c) v = acc[c];
        st_agent(&ag[b * 3072 + j0 + ln], v + pre);
      }
    }
    gbar(barcnt, 2 * t);

    {
      int b = wv;
      const float* agv = ag + b * 3072;
      float pr = 0.f;
      if (ln < 4) pr = preR[((size_t)((b << 10) + t) << 10) + j2 + ln];

      float4 g0, g1, g2, g3, a0, a1, a2, a3, a4, a5, a6, a7;
      ldg_phase2(agv + 2048 + (ln << 2), agv + (ln << 2),
                 g0, g1, g2, g3, a0, a1, a2, a3, a4, a5, a6, a7);
      float4 gv_[4] = {g0, g1, g2, g3};
      float4 av_[8] = {a0, a1, a2, a3, a4, a5, a6, a7};

      float gs = 0.f;
#pragma unroll
      for (int i = 0; i < 4; ++i) {
        int gi = ((i << 6) + ln) << 2;
        uint2 wq = *(const uint2*)&wg2l[gi];
        gs = fmaf(tanh_fast(gv_[i].x), blo(wq.x), gs);
        gs = fmaf(tanh_fast(gv_[i].y), bhi(wq.x), gs);
        gs = fmaf(tanh_fast(gv_[i].z), blo(wq.y), gs);
        gs = fmaf(tanh_fast(gv_[i].w), bhi(wq.y), gs);
      }
#pragma unroll
      for (int off = 32; off; off >>= 1) gs += __shfl_xor(gs, off);
      float gate = 1.f / (1.f + exp2f(-1.4426950408889634f * (gs + bg2v)));

      float acc2[4] = {0.f, 0.f, 0.f, 0.f};
#pragma unroll
      for (int i = 0; i < 8; ++i) {
        int kk = (i << 8) + (ln << 2);
        float ax = fmaxf(av_[i].x, 0.f), ay = fmaxf(av_[i].y, 0.f);
        float az = fmaxf(av_[i].z, 0.f), aw = fmaxf(av_[i].w, 0.f);
#pragma unroll
        for (int c = 0; c < 4; ++c) {
          uint2 wq = *(const uint2*)&w2[c * 2048 + kk];
          float a = acc2[c];
          a = fmaf(blo(wq.x), ax, a); a = fmaf(bhi(wq.x), ay, a);
          a = fmaf(blo(wq.y), az, a); a = fmaf(bhi(wq.y), aw, a);
          acc2[c] = a;
        }
      }
#pragma unroll
      for (int c = 0; c < 4; ++c) {
        float v = acc2[c];
#pragma unroll
        for (int off = 32; off; off >>= 1) v += __shfl_xor(v, off);
        acc2[c] = v;
      }
      if (ln < 4) {
        float cand = acc2[0];
#pragma unroll
        for (int c = 1; c < 4; ++c) if (ln == c) cand = acc2[c];
        cand += b2l[ln];
        float h1v = hnf[p * 4096 + (b << 10) + j2 + ln];
        st_agent(&hbuf[(b << 10) + j2 + ln], h1v + gate * cand + pr);
      }
    }
    gbar(barcnt, 2 * t + 1);
  }
}

// ---------------- windowed attention (W=8, 9 taps) ----------------
__global__ __launch_bounds__(256) void attn_kernel(
    const float* __restrict__ q, const float* __restrict__ kk,
    const float* __restrict__ vv, float* __restrict__ o)
{
  int m = blockIdx.x;           // b*T + t
  int t = m & 1023;
  int tid = threadIdx.x;
  int ln = tid & 63, wvv = tid >> 6;
  int c0 = tid << 2;
  __shared__ float sred[36];

  float4 qv = *(const float4*)&q[((size_t)m << 10) + c0];
#pragma unroll
  for (int w = 0; w < 9; ++w) {
    int src = t + w - 8;
    float s = 0.f;
    if (src >= 0) {
      float4 kv = *(const float4*)&kk[((size_t)(m + w - 8) << 10) + c0];
      s = qv.x * kv.x + qv.y * kv.y + qv.z * kv.z + qv.w * kv.w;
    }
#pragma unroll
    for (int off = 32; off; off >>= 1) s += __shfl_xor(s, off);
    if (ln == 0) sred[w * 4 + wvv] = s;
  }
  __syncthreads();

  float p[9], mx = -3.4e38f;
#pragma unroll
  for (int w = 0; w < 9; ++w) {
    if (t + w - 8 >= 0) {
      float sc = (sred[w * 4] + sred[w * 4 + 1] + sred[w * 4 + 2] + sred[w * 4 + 3]) * 0.03125f;
      p[w] = sc; mx = fmaxf(mx, sc);
    } else p[w] = -3.4e38f;
  }
  float den = 0.f;
#pragma unroll
  for (int w = 0; w < 9; ++w) {
    float e = (t + w - 8 >= 0) ? exp2f(1.4426950408889634f * (p[w] - mx)) : 0.f;
    p[w] = e; den += e;
  }
  float inv = 1.f / den;
  float4 acc = {0.f, 0.f, 0.f, 0.f};
#pragma unroll
  for (int w = 0; w < 9; ++w) {
    if (t + w - 8 >= 0) {
      float4 vr = *(const float4*)&vv[((size_t)(m + w - 8) << 10) + c0];
      float pw = p[w] * inv;
      acc.x = fmaf(pw, vr.x, acc.x); acc.y = fmaf(pw, vr.y, acc.y);
      acc.z = fmaf(pw, vr.z, acc.z); acc.w = fmaf(pw, vr.w, acc.w);
    }
  }
  *(float4*)&o[((size_t)m << 10) + c0] = acc;
}

// ---------------- workspace layout (bytes) ----------------
constexpr size_t OFF_STATES = 0;                       // 4096*1024 f32 = 16.8 MB
constexpr size_t OFF_PREA   = 16777216;                // 4096*2048 f32 = 33.5 MB
constexpr size_t OFF_PREG   = 50331648;                // 16.8 MB
constexpr size_t OFF_PRER   = 67108864;                // 16.8 MB
constexpr size_t OFF_AG     = 83886080;                // 4*3072 f32
constexpr size_t OFF_HB     = 83935232;                // 4*1024 f32
constexpr size_t OFF_CNT    = 83951616;                // flag array: 256 x 64 B
constexpr size_t CNT_BYTES  = 16384;
constexpr size_t NEED_WS    = 83968000;

extern "C" void kernel_launch(void* const* d_in, const int* in_sizes, int n_in,
                              void* d_out, int out_size, void* d_ws, size_t ws_size,
                              hipStream_t stream) {
  const int*   x   = (const int*)d_in[0];
  const float* emb = (const float*)d_in[1];
  const float* W1c = (const float*)d_in[2];
  const float* b1c = (const float*)d_in[3];
  const float* W2c = (const float*)d_in[4];
  const float* b2c = (const float*)d_in[5];
  const float* Wg1 = (const float*)d_in[6];
  const float* bg1 = (const float*)d_in[7];
  const float* Wg2 = (const float*)d_in[8];
  const float* bg2 = (const float*)d_in[9];
  const float* Wr  = (const float*)d_in[10];
  const float* br  = (const float*)d_in[11];
  const float* Wk  = (const float*)d_in[12];
  const float* bk  = (const float*)d_in[13];
  const float* Wq  = (const float*)d_in[14];
  const float* bq  = (const float*)d_in[15];
  const float* Wv  = (const float*)d_in[16];
  const float* bv  = (const float*)d_in[17];
  const float* Wf  = (const float*)d_in[18];
  const float* bfv = (const float*)d_in[19];

  if (ws_size < NEED_WS) return;
  char* ws = (char*)d_ws;
  float* states = (float*)(ws + OFF_STATES);
  float* preA = (float*)(ws + OFF_PREA);
  float* preG = (float*)(ws + OFF_PREG);
  float* preR = (float*)(ws + OFF_PRER);
  float* agb  = (float*)(ws + OFF_AG);
  float* hbuf = (float*)(ws + OFF_HB);
  unsigned* barcnt = (unsigned*)(ws + OFF_CNT);

  dim3 blk(256);
  hipMemsetAsync(barcnt, 0, CNT_BYTES, stream);

  // precompute et-dependent parts (gathered-embedding GEMMs, K=512), biases folded in
  gemm_kernel<<<dim3(32, 64), blk, 0, stream>>>(nullptr, emb, x, W1c + (size_t)2048 * 2048, 2048,
                                                b1c, 1.f, preA, 4096, 2048, 512);
  gemm_kernel<<<dim3(16, 64), blk, 0, stream>>>(nullptr, emb, x, Wg1 + (size_t)2048 * 1024, 1024,
                                                bg1, 1.f, preG, 4096, 1024, 512);
  gemm_kernel<<<dim3(16, 64), blk, 0, stream>>>(nullptr, emb, x, Wr, 1024,
                                                br, 0.1f, preR, 4096, 1024, 512);

  // persistent cooperative recurrence
  hipFuncSetAttribute((const void*)recur_kernel,
                      hipFuncAttributeMaxDynamicSharedMemorySize, RC_LDS_BYTES);
  void* args[] = {(void*)&W1c, (void*)&Wg1, (void*)&W2c, (void*)&b2c, (void*)&Wg2, (void*)&bg2,
                  (void*)&preA, (void*)&preG, (void*)&preR,
                  (void*)&states, (void*)&agb, (void*)&hbuf, (void*)&barcnt};
  hipLaunchCooperativeKernel((const void*)recur_kernel, dim3(256), dim3(256),
                             args, RC_LDS_BYTES, stream);

  // q/k/v reuse the pre-buffers (no longer needed after the scan)
  float* qb = preA;
  float* kb = preA + 4194304;   // second 16.8 MB half of preA
  float* vb = preG;
  float* ab = preR;
  gemm_kernel<<<dim3(16, 64), blk, 0, stream>>>(states, nullptr, nullptr, Wq, 1024,
                                                bq, 1.f, qb, 4096, 1024, 1024);
  gemm_kernel<<<dim3(16, 64), blk, 0, stream>>>(states, nullptr, nullptr, Wk, 1024,
                                                bk, 1.f, kb, 4096, 1024, 1024);
  gemm_kernel<<<dim3(16, 64), blk, 0, stream>>>(states, nullptr, nullptr, Wv, 1024,
                                                bv, 1.f, vb, 4096, 1024, 1024);
  attn_kernel<<<dim3(4096), blk, 0, stream>>>(qb, kb, vb, ab);
  // final 268-GFLOP output GEMM: bf16x3 MFMA (805 GF effective), 250x32 tiles
  mfma_gemm<<<dim3(8000), blk, 0, stream>>>(ab, Wf, bfv, (float*)d_out);
}